// Round 8
// baseline (329.078 us; speedup 1.0000x reference)
//
#include <hip/hip_runtime.h>
#include <math.h>
#include <stdint.h>

#define B_    4
#define N_    2048
#define DIM_  1024
#define H_    16
#define DH_   64
#define HID_  1024
#define RS_   3072          // qkv row stride (3*HID)
#define C2_   0.1803368801111204f   // (1/sqrt(64)) * log2(e), folded into Q columns of w_qkv

typedef unsigned short u16;
typedef unsigned int   u32;
typedef short  bf16x8 __attribute__((ext_vector_type(8)));   // 8 bf16 = 4 VGPRs (MFMA A/B frag)
typedef u16    u16x8  __attribute__((ext_vector_type(8)));   // 16B vector for bf16 data movement
typedef float  f32x4  __attribute__((ext_vector_type(4)));   // 16x16 MFMA C/D frag
typedef float  f32x16 __attribute__((ext_vector_type(16)));  // 32x32 MFMA C/D frag
typedef unsigned int u32x2 __attribute__((ext_vector_type(2)));

__device__ inline u16 f2b(float x) {   // fp32 -> bf16, round-to-nearest-even
    u32 u = __float_as_uint(x);
    return (u16)((u + 0x7fffu + ((u >> 16) & 1u)) >> 16);
}
__device__ inline float b2f(u16 x) {
    return __uint_as_float((u32)x << 16);
}

// pack two fp32 -> two bf16 (round-half-up) in one u32: [hi16(f1) : hi16(f0)]
// KNOWN-GOOD. v_cvt_pk_bf16_f32 PERMANENTLY REJECTED (R1 vs R3 isolation:
// identical permlane routing, cvt_pk fails at 4.7e-2, pack2bf passes).
__device__ inline u32 pack2bf(float f0, float f1) {
    u32 u0 = __float_as_uint(f0) + 0x8000u;
    u32 u1 = __float_as_uint(f1) + 0x8000u;
    return __builtin_amdgcn_perm(u1, u0, 0x07060302u);
}

// v_permlane32_swap_b32 vdst, src:  vdst.row[1] <-> src.row[0]
// VERIFIED on HW in R3 (absmax 1.95e-3 baseline-class).
__device__ inline void pl32swap(u32 &a, u32 &b) {
#if __has_builtin(__builtin_amdgcn_permlane32_swap)
    u32x2 r = __builtin_amdgcn_permlane32_swap(a, b, false, false);
    a = r[0]; b = r[1];
#else
    asm("v_permlane32_swap_b32 %0, %1" : "+v"(a), "+v"(b));
#endif
}

#if defined(__has_builtin)
#if __has_builtin(__builtin_amdgcn_global_load_lds)
#define USE_GLL 1
#endif
#endif

#ifdef USE_GLL
typedef const __attribute__((address_space(1))) u32* gas_ptr;
typedef __attribute__((address_space(3))) u32* las_ptr;
__device__ inline void gll16(const void* g, void* l) {
    __builtin_amdgcn_global_load_lds((gas_ptr)g, (las_ptr)l, 16, 0, 0);
}
#endif

// ---------------------------------------------------------------------------
// Elementwise fp32 -> bf16 cast (x). 8 elems/thread.
// ---------------------------------------------------------------------------
__global__ __launch_bounds__(256) void cast_bf16(const float* __restrict__ in,
                                                 u16* __restrict__ out, int n) {
    int i = (blockIdx.x * 256 + threadIdx.x) * 8;
    if (i >= n) return;
    float4 a = *(const float4*)&in[i];
    float4 b = *(const float4*)&in[i + 4];
    u16x8 p;
    p[0] = f2b(a.x); p[1] = f2b(a.y); p[2] = f2b(a.z); p[3] = f2b(a.w);
    p[4] = f2b(b.x); p[5] = f2b(b.y); p[6] = f2b(b.z); p[7] = f2b(b.w);
    *(u16x8*)&out[i] = p;
}

// ---------------------------------------------------------------------------
// W[K][Nn] fp32 -> Wt[Nn][K] bf16 (64x64 tiles). Columns < qcols scaled by C2
// (folds the attention scale*log2e into the Q projection once).
// ---------------------------------------------------------------------------
__global__ __launch_bounds__(256) void transpose_cast(const float* __restrict__ W,
                                                      u16* __restrict__ Wt,
                                                      int K, int Nn, int qcols) {
    __shared__ float t[64][65];
    const int tid = threadIdx.x;
    const int k0 = blockIdx.y * 64, n0 = blockIdx.x * 64;
    for (int idx = tid; idx < 64 * 16; idx += 256) {
        int r = idx >> 4, c4 = (idx & 15) * 4;
        float4 g = *(const float4*)&W[(size_t)(k0 + r) * Nn + n0 + c4];
        t[r][c4] = g.x; t[r][c4 + 1] = g.y; t[r][c4 + 2] = g.z; t[r][c4 + 3] = g.w;
    }
    __syncthreads();
    for (int idx = tid; idx < 64 * 8; idx += 256) {
        int n = idx >> 3, k8 = (idx & 7) * 8;
        float s = (n0 + n < qcols) ? C2_ : 1.0f;
        u16x8 p;
        #pragma unroll
        for (int u = 0; u < 8; u++) p[u] = f2b(t[k8 + u][n] * s);
        *(u16x8*)&Wt[(size_t)(n0 + n) * K + k0 + k8] = p;
    }
}

// ---------------------------------------------------------------------------
// GEMM (BT form): C[M][Nn] = A[M][K] . Bt[Nn][K]^T (+bias), bf16 in, MFMA.
// 128x128 tile, 256 thr (4 waves in 2x2), 4x4 16x16x32 tiles/wave.
// R15 (verified win, R7: gemm left the top-5; conflicts 6.3M -> ~0):
// BK=64 (32 MFMA per barrier-pair) + XOR LDS swizzle via pre-swizzled
// gll16 global source (rule #21 CORRECT case) + swizzled ds_read.
// 1-D grid, XCD-swizzled. [R8: swizzle worth ~-15us on the two gemms.]
// ---------------------------------------------------------------------------
template<int BF16OUT>
__global__ __launch_bounds__(256) void gemm_bt(const u16* __restrict__ A,
                                               const u16* __restrict__ Bt,
                                               const float* __restrict__ bias,
                                               void* __restrict__ Cout,
                                               int M, int Nn, int K) {
    __shared__ u16 at[128 * 64];
    __shared__ u16 bt[128 * 64];
    const int tid = threadIdx.x;
    const int lane = tid & 63, wave = tid >> 6;
    const int wr = wave >> 1, wc = wave & 1;
    const int mlane = lane & 15, quad = lane >> 4;
    const int id = blockIdx.x;
    const int mt = (id & 7) * 8 + ((id >> 3) & 7);
    const int nt = id >> 6;
    const int m0 = mt * 128, n0 = nt * 128;
    const int r = tid >> 3, kc = (tid & 7) * 8;      // staging row 0..31, col chunk
    const int kcs = kc ^ ((r & 7) * 8);              // inverse-swizzled source col

    f32x4 acc[4][4] = {};

    for (int k0 = 0; k0 < K; k0 += 64) {
        __syncthreads();
#ifdef USE_GLL
        #pragma unroll
        for (int i = 0; i < 4; i++) {
            gll16(&A [(size_t)(m0 + r + 32 * i) * K + k0 + kcs], &at[(r + 32 * i) * 64 + kc]);
            gll16(&Bt[(size_t)(n0 + r + 32 * i) * K + k0 + kcs], &bt[(r + 32 * i) * 64 + kc]);
        }
#else
        #pragma unroll
        for (int i = 0; i < 4; i++) {
            *(u16x8*)&at[(r + 32 * i) * 64 + kc] = *(const u16x8*)&A [(size_t)(m0 + r + 32 * i) * K + k0 + kcs];
            *(u16x8*)&bt[(r + 32 * i) * 64 + kc] = *(const u16x8*)&Bt[(size_t)(n0 + r + 32 * i) * K + k0 + kcs];
        }
#endif
        __syncthreads();

        #pragma unroll
        for (int ks = 0; ks < 2; ks++) {
            bf16x8 af[4], bf[4];
            #pragma unroll
            for (int rt = 0; rt < 4; rt++) {
                int row = wr * 64 + rt * 16 + mlane;
                af[rt] = *(const bf16x8*)&at[row * 64 + ((ks * 32 + quad * 8) ^ ((row & 7) * 8))];
            }
            #pragma unroll
            for (int ct = 0; ct < 4; ct++) {
                int row = wc * 64 + ct * 16 + mlane;
                bf[ct] = *(const bf16x8*)&bt[row * 64 + ((ks * 32 + quad * 8) ^ ((row & 7) * 8))];
            }
            #pragma unroll
            for (int rt = 0; rt < 4; rt++)
                #pragma unroll
                for (int ct = 0; ct < 4; ct++)
                    acc[rt][ct] = __builtin_amdgcn_mfma_f32_16x16x32_bf16(af[rt], bf[ct], acc[rt][ct], 0, 0, 0);
        }
    }

    const int row0 = m0 + wr * 64 + quad * 4;
    const int col0 = n0 + wc * 64 + mlane;
    #pragma unroll
    for (int rt = 0; rt < 4; rt++)
        #pragma unroll
        for (int ct = 0; ct < 4; ct++) {
            int c = col0 + ct * 16;
            float bv = (!BF16OUT && bias != nullptr) ? bias[c] : 0.f;
            #pragma unroll
            for (int reg = 0; reg < 4; reg++) {
                int rr = row0 + rt * 16 + reg;
                float v = acc[rt][ct][reg] + bv;
                if (BF16OUT) ((u16*)Cout)[(size_t)rr * Nn + c] = f2b(v);
                else         ((float*)Cout)[(size_t)rr * Nn + c] = v;
            }
        }
}

// ---------------------------------------------------------------------------
// FUSED stats + V-transpose. Per (head, 64-key tile) block:
//  1) invl_j = 1 / sum_i exp2(qs_i.k_j) over all queries (MFMA S^T sweep);
//  2) vT[bh][d][j] = v[b,j,h,d] * invl_j.
// ---------------------------------------------------------------------------
__global__ __launch_bounds__(256) void attn_stats_vt(const u16* __restrict__ qkvb,
                                                     u16* __restrict__ vT) {
    __shared__ u16 kt[64 * 72];       // K tile, then reused as the V tile
    __shared__ u16 qt[4][64 * 72];
    __shared__ float red[4][64];
    __shared__ float li[64];

    const int tid = threadIdx.x;
    const int lane = tid & 63, wave = tid >> 6;
    const int mlane = lane & 15, quad = lane >> 4;
    const int id = blockIdx.x;
    const int bh = (id & 7) * 8 + ((id >> 3) & 7);
    const int b = bh >> 4, h = bh & 15;
    const int j0 = (id >> 6) * 64;

    const u16* qbase = qkvb + (size_t)b * N_ * RS_ + h * DH_;
    const u16* kbase = qbase + HID_;
    const u16* vbase = qbase + 2 * HID_;

    // K tile (pure copy; scale already folded into Q)
    for (int idx = tid; idx < 512; idx += 256) {
        int r = idx >> 3, d8 = (idx & 7) * 8;
        *(u16x8*)&kt[r * 72 + d8] = *(const u16x8*)&kbase[(size_t)(j0 + r) * RS_ + d8];
    }
    __syncthreads();

    // hoist K A-frags (loop-invariant)
    bf16x8 kf[4][2];
    #pragma unroll
    for (int t = 0; t < 4; t++)
        #pragma unroll
        for (int ks = 0; ks < 2; ks++)
            kf[t][ks] = *(const bf16x8*)&kt[(t * 16 + mlane) * 72 + ks * 32 + quad * 8];

    f32x4 acc[4] = {};   // acc[ktile][reg] : key = ktile*16 + quad*4 + reg
    u16* qw = &qt[wave][0];

    const int prr = lane >> 3, pd8 = (lane & 7) * 8;   // per-lane staging coords
    u16x8 pq[8];
    #pragma unroll
    for (int t = 0; t < 8; t++)
        pq[t] = *(const u16x8*)&qbase[(size_t)(wave * 64 + t * 8 + prr) * RS_ + pd8];

    for (int i0 = wave * 64; i0 < N_; i0 += 256) {
        #pragma unroll
        for (int t = 0; t < 8; t++)
            *(u16x8*)&qw[(t * 8 + prr) * 72 + pd8] = pq[t];
        int in = i0 + 256;
        if (in < N_) {
            #pragma unroll
            for (int t = 0; t < 8; t++)
                pq[t] = *(const u16x8*)&qbase[(size_t)(in + t * 8 + prr) * RS_ + pd8];
        }
        #pragma unroll
        for (int q4 = 0; q4 < 4; q4++) {
            bf16x8 bq0 = *(const bf16x8*)&qw[(q4 * 16 + mlane) * 72 + quad * 8];
            bf16x8 bq1 = *(const bf16x8*)&qw[(q4 * 16 + mlane) * 72 + 32 + quad * 8];
            #pragma unroll
            for (int t = 0; t < 4; t++) {
                f32x4 z = {0.f, 0.f, 0.f, 0.f};
                z = __builtin_amdgcn_mfma_f32_16x16x32_bf16(kf[t][0], bq0, z, 0, 0, 0);
                z = __builtin_amdgcn_mfma_f32_16x16x32_bf16(kf[t][1], bq1, z, 0, 0, 0);
                #pragma unroll
                for (int reg = 0; reg < 4; reg++)
                    acc[t][reg] += __builtin_amdgcn_exp2f(z[reg]);
            }
        }
    }

    #pragma unroll
    for (int t = 0; t < 4; t++)
        #pragma unroll
        for (int reg = 0; reg < 4; reg++) {
            float v = acc[t][reg];
            v += __shfl_xor(v, 1, 64);
            v += __shfl_xor(v, 2, 64);
            v += __shfl_xor(v, 4, 64);
            v += __shfl_xor(v, 8, 64);
            if (mlane == 0) red[wave][t * 16 + quad * 4 + reg] = v;
        }
    __syncthreads();
    if (tid < 64) {
        float l = red[0][tid] + red[1][tid] + red[2][tid] + red[3][tid];
        li[tid] = 1.0f / l;
    }

    // --- phase 2: V tile scale + transpose (reuse kt buffer) ---
    for (int idx = tid; idx < 512; idx += 256) {
        int r = idx >> 3, d8 = (idx & 7) * 8;
        *(u16x8*)&kt[r * 72 + d8] = *(const u16x8*)&vbase[(size_t)(j0 + r) * RS_ + d8];
    }
    __syncthreads();   // covers li writes and V staging
    {
        int d = tid >> 2, j16 = (tid & 3) * 16;
        u16x8 p0, p1;
        #pragma unroll
        for (int u = 0; u < 8; u++) {
            p0[u] = f2b(b2f(kt[(j16 + u) * 72 + d]) * li[j16 + u]);
            p1[u] = f2b(b2f(kt[(j16 + 8 + u) * 72 + d]) * li[j16 + 8 + u]);
        }
        size_t o = ((size_t)bh * DH_ + d) * N_ + j0 + j16;
        *(u16x8*)&vT[o] = p0;
        *(u16x8*)&vT[o + 8] = p1;
    }
}

// ---------------------------------------------------------------------------
// Apply (32x32 MFMA): S^T = K.Qs^T -> P = exp2(S^T) (registers, permlane
// exchange to A-layout, verified R3) -> Y += P.V'.
// R14 structure kept (77us plateau): 256 q/block, 8 waves, K/V dbuf,
// single barrier per j-tile, setprio on MFMA clusters.
// R16 (this round): XCD-bijective grid swizzle. The old 2D grid dispatched
// the 8 i-blocks of one bh consecutively -> spread over 8 XCDs -> K/vT
// (512 KB/bh) replicated per-XCD L2 (measured FETCH 139 MB vs ~50 logical).
// Now 1-D grid 512: v=(id&7)*64+(id>>3) -> each XCD owns 8 bh x all 8
// i-blocks; K/vT per XCD = 4 MB = one L2. R4 proved this mapping cuts
// FETCH ~5x on this kernel family.
// ---------------------------------------------------------------------------
__global__ __launch_bounds__(512) void attn_apply(const u16* __restrict__ qkvb,
                                                  const u16* __restrict__ vT,
                                                  u16* __restrict__ yb) {
    __shared__ u16 S[256 * 72];   // Q (256x64) at start; then dbuf: buf0 rows 0..127, buf1 rows 128..255

    const int tid = threadIdx.x;
    const int lane = tid & 63, wave = tid >> 6;   // wave 0..7
    const int m31 = lane & 31, half = lane >> 5;

    const int id = blockIdx.x;
    const int v = (id & 7) * 64 + (id >> 3);      // XCD-bijective swizzle (512%8==0)
    const int bh = v >> 3, b = bh >> 4, h = bh & 15;
    const int i0 = (v & 7) * 256;

    const u16* qbase = qkvb + (size_t)b * N_ * RS_ + h * DH_;
    const u16* kbase = qbase + HID_;
    const u16* vbase = vT + (size_t)bh * DH_ * N_;

    // stage Q: 256 rows x 64 dims = 2048 chunks (Q pre-scaled by C2 upstream)
    for (int idx = tid; idx < 2048; idx += 512) {
        int r = idx >> 3, d8 = (idx & 7) * 8;
        *(u16x8*)&S[r * 72 + d8] = *(const u16x8*)&qbase[(size_t)(i0 + r) * RS_ + d8];
    }
    __syncthreads();

    // hoist Q B-frags: qf[kstep], query = wave*32 + m31
    bf16x8 qf[4];
    #pragma unroll
    for (int ks = 0; ks < 4; ks++)
        qf[ks] = *(const bf16x8*)&S[(wave * 32 + m31) * 72 + ks * 16 + half * 8];

    // prefetch tile 0: 1 K-chunk + 1 V-chunk per thread (512 thr)
    const int pr = tid >> 3, pc8 = (tid & 7) * 8;   // pr 0..63
    u16x8 pk, pv;
    pk = *(const u16x8*)&kbase[(size_t)pr * RS_ + pc8];
    pv = *(const u16x8*)&vbase[(size_t)pr * N_ + pc8];

    __syncthreads();   // all waves done hoisting qf (about to clobber Q rows)

    f32x16 yacc[2] = {};   // [dtile]

    int cur = 0;
    for (int j0 = 0; j0 < N_; j0 += 64, cur ^= 1) {
        u16* Sb = &S[cur * 128 * 72];
        *(u16x8*)&Sb[pr * 72 + pc8]        = pk;   // K rows 0..63
        *(u16x8*)&Sb[(pr + 64) * 72 + pc8] = pv;   // vT rows 0..63 at offset 64
        __syncthreads();   // writes visible; prev buffer's readers implicitly done

        int jn = j0 + 64;
        if (jn < N_) {   // issue next tile's loads; land in buf[cur^1] next iter
            pk = *(const u16x8*)&kbase[(size_t)(jn + pr) * RS_ + pc8];
            pv = *(const u16x8*)&vbase[(size_t)pr * N_ + jn + pc8];
        }

        // --- S^T + P, per 32-key tile kt ---
        bf16x8 pa[4];   // PV A-frags [ks16]
        #pragma unroll
        for (int kt = 0; kt < 2; kt++) {
            bf16x8 ka[4];
            #pragma unroll
            for (int ks = 0; ks < 4; ks++)
                ka[ks] = *(const bf16x8*)&Sb[(kt * 32 + m31) * 72 + ks * 16 + half * 8];

            f32x16 sc = {};
            __builtin_amdgcn_s_setprio(1);
            #pragma unroll
            for (int ks = 0; ks < 4; ks++)
                sc = __builtin_amdgcn_mfma_f32_32x32x16_bf16(ka[ks], qf[ks], sc, 0, 0, 0);
            __builtin_amdgcn_s_setprio(0);

            // exp2 -> pack (P[rb][pp] = keys 8rb + 4half + 2pp + {0,1}) ->
            // permlane32_swap (verified R3) to A-layout.
            u32 P[4][2];
            #pragma unroll
            for (int rb = 0; rb < 4; rb++)
                #pragma unroll
                for (int pp = 0; pp < 2; pp++) {
                    float e0 = __builtin_amdgcn_exp2f(sc[4 * rb + 2 * pp]);
                    float e1 = __builtin_amdgcn_exp2f(sc[4 * rb + 2 * pp + 1]);
                    P[rb][pp] = pack2bf(e0, e1);
                }
            #pragma unroll
            for (int ksl = 0; ksl < 2; ksl++) {
                pl32swap(P[2 * ksl][0], P[2 * ksl + 1][0]);
                pl32swap(P[2 * ksl][1], P[2 * ksl + 1][1]);
                union { u32 u[4]; bf16x8 v; } cv;
                cv.u[0] = P[2 * ksl][0];
                cv.u[1] = P[2 * ksl][1];
                cv.u[2] = P[2 * ksl + 1][0];
                cv.u[3] = P[2 * ksl + 1][1];
                pa[2 * kt + ksl] = cv.v;
            }
        }

        // --- Y += P @ V' (V pre-scaled by invl) ---
        __builtin_amdgcn_s_setprio(1);
        #pragma unroll
        for (int ks16 = 0; ks16 < 4; ks16++) {
            bf16x8 vb0 = *(const bf16x8*)&Sb[(64 + m31) * 72 + ks16 * 16 + half * 8];
            bf16x8 vb1 = *(const bf16x8*)&Sb[(96 + m31) * 72 + ks16 * 16 + half * 8];
            yacc[0] = __builtin_amdgcn_mfma_f32_32x32x16_bf16(pa[ks16], vb0, yacc[0], 0, 0, 0);
            yacc[1] = __builtin_amdgcn_mfma_f32_32x32x16_bf16(pa[ks16], vb1, yacc[1], 0, 0, 0);
        }
        __builtin_amdgcn_s_setprio(0);
    }

    // epilogue: query = i0 + wave*32 + (reg&3)+8*(reg>>2)+4*half, d = dt*32+m31
    #pragma unroll
    for (int dt = 0; dt < 2; dt++)
        #pragma unroll
        for (int reg = 0; reg < 16; reg++) {
            int q = i0 + wave * 32 + (reg & 3) + 8 * (reg >> 2) + 4 * half;
            yb[((size_t)b * N_ + q) * HID_ + h * DH_ + dt * 32 + m31] = f2b(yacc[dt][reg]);
        }
}

// ---------------------------------------------------------------------------
extern "C" void kernel_launch(void* const* d_in, const int* in_sizes, int n_in,
                              void* d_out, int out_size, void* d_ws, size_t ws_size,
                              hipStream_t stream) {
    (void)in_sizes; (void)n_in; (void)out_size; (void)ws_size;

    const float* x     = (const float*)d_in[0];
    const float* w_qkv = (const float*)d_in[1];
    const float* w_out = (const float*)d_in[2];
    const float* b_out = (const float*)d_in[3];

    u16* xb    = (u16*)d_ws;                          // [8192][1024]
    u16* wqkvT = xb    + (size_t)8192 * 1024;         // [3072][1024]
    u16* woutT = wqkvT + (size_t)3072 * 1024;         // [1024][1024]
    u16* qkvb  = woutT + (size_t)1024 * 1024;         // [8192][3072]
    u16* vTb   = qkvb  + (size_t)8192 * 3072;         // [64][64][2048]
    u16* yb    = vTb   + (size_t)64 * 64 * 2048;      // [8192][1024]

    cast_bf16<<<4096, 256, 0, stream>>>(x, xb, 8192 * 1024);
    transpose_cast<<<dim3(3072 / 64, 1024 / 64), 256, 0, stream>>>(w_qkv, wqkvT, 1024, 3072, HID_);
    transpose_cast<<<dim3(1024 / 64, 1024 / 64), 256, 0, stream>>>(w_out, woutT, 1024, 1024, 0);

    // grid = 64 m-tiles * 24 n-tiles, XCD-swizzled inside the kernel
    gemm_bt<1><<<64 * 24, 256, 0, stream>>>(
        xb, wqkvT, nullptr, qkvb, 8192, 3072, 1024);

    // fused stats + V-transpose: grid = 32 j-tiles * 64 heads, XCD-swizzled
    attn_stats_vt<<<32 * 64, 256, 0, stream>>>(qkvb, vTb);

    // R16 shape: 256 q/block, 8 waves (512 thr), 1-D grid 512, XCD swizzle
    attn_apply<<<512, 512, 0, stream>>>(qkvb, vTb, yb);

    // grid = 64 m-tiles * 8 n-tiles, XCD-swizzled
    gemm_bt<0><<<64 * 8, 256, 0, stream>>>(
        yb, woutT, b_out, d_out, 8192, 1024, 1024);
}

// Round 10
// 321.350 us; speedup vs baseline: 1.0240x; 1.0240x over previous
//
#include <hip/hip_runtime.h>
#include <math.h>
#include <stdint.h>

#define B_    4
#define N_    2048
#define DIM_  1024
#define H_    16
#define DH_   64
#define HID_  1024
#define RS_   3072          // qkv row stride (3*HID)
#define C2_   0.1803368801111204f   // (1/sqrt(64)) * log2(e), folded into Q columns of w_qkv

typedef unsigned short u16;
typedef unsigned int   u32;
typedef short  bf16x8 __attribute__((ext_vector_type(8)));   // 8 bf16 = 4 VGPRs (MFMA A/B frag)
typedef u16    u16x8  __attribute__((ext_vector_type(8)));   // 16B vector for bf16 data movement
typedef float  f32x4  __attribute__((ext_vector_type(4)));   // 16x16 MFMA C/D frag
typedef float  f32x16 __attribute__((ext_vector_type(16)));  // 32x32 MFMA C/D frag
typedef unsigned int u32x2 __attribute__((ext_vector_type(2)));

__device__ inline u16 f2b(float x) {   // fp32 -> bf16, round-to-nearest-even
    u32 u = __float_as_uint(x);
    return (u16)((u + 0x7fffu + ((u >> 16) & 1u)) >> 16);
}
__device__ inline float b2f(u16 x) {
    return __uint_as_float((u32)x << 16);
}

// pack two fp32 -> two bf16 (round-half-up). KNOWN-GOOD (R3).
__device__ inline u32 pack2bf(float f0, float f1) {
    u32 u0 = __float_as_uint(f0) + 0x8000u;
    u32 u1 = __float_as_uint(f1) + 0x8000u;
    return __builtin_amdgcn_perm(u1, u0, 0x07060302u);
}

// v_permlane32_swap_b32: vdst.row[1] <-> src.row[0]. VERIFIED R3.
__device__ inline void pl32swap(u32 &a, u32 &b) {
#if __has_builtin(__builtin_amdgcn_permlane32_swap)
    u32x2 r = __builtin_amdgcn_permlane32_swap(a, b, false, false);
    a = r[0]; b = r[1];
#else
    asm("v_permlane32_swap_b32 %0, %1" : "+v"(a), "+v"(b));
#endif
}

// R10 fix: gll16 must be DECLARED in the host pass too (host clang parses
// __global__ bodies; R9 failed to compile because the macro call sites were
// unguarded while the definition was #ifdef'd on a device-only builtin).
// Builtin selected at device compile; host-parse fallback is a plain copy
// (never codegen'd for gfx950 device code).
typedef const __attribute__((address_space(1))) u32* gas_ptr;
typedef __attribute__((address_space(3))) u32* las_ptr;
__device__ inline void gll16(const void* g, void* l) {
#if defined(__HIP_DEVICE_COMPILE__) && __has_builtin(__builtin_amdgcn_global_load_lds)
    __builtin_amdgcn_global_load_lds((gas_ptr)g, (las_ptr)l, 16, 0, 0);
#else
    *(u16x8*)l = *(const u16x8*)g;
#endif
}

// ---------------------------------------------------------------------------
// Elementwise fp32 -> bf16 cast (x). 8 elems/thread.
// ---------------------------------------------------------------------------
__global__ __launch_bounds__(256) void cast_bf16(const float* __restrict__ in,
                                                 u16* __restrict__ out, int n) {
    int i = (blockIdx.x * 256 + threadIdx.x) * 8;
    if (i >= n) return;
    float4 a = *(const float4*)&in[i];
    float4 b = *(const float4*)&in[i + 4];
    u16x8 p;
    p[0] = f2b(a.x); p[1] = f2b(a.y); p[2] = f2b(a.z); p[3] = f2b(a.w);
    p[4] = f2b(b.x); p[5] = f2b(b.y); p[6] = f2b(b.z); p[7] = f2b(b.w);
    *(u16x8*)&out[i] = p;
}

// ---------------------------------------------------------------------------
// W[K][Nn] fp32 -> Wt[Nn][K] bf16 (64x64 tiles). Columns < qcols scaled by C2.
// ---------------------------------------------------------------------------
__global__ __launch_bounds__(256) void transpose_cast(const float* __restrict__ W,
                                                      u16* __restrict__ Wt,
                                                      int K, int Nn, int qcols) {
    __shared__ float t[64][65];
    const int tid = threadIdx.x;
    const int k0 = blockIdx.y * 64, n0 = blockIdx.x * 64;
    for (int idx = tid; idx < 64 * 16; idx += 256) {
        int r = idx >> 4, c4 = (idx & 15) * 4;
        float4 g = *(const float4*)&W[(size_t)(k0 + r) * Nn + n0 + c4];
        t[r][c4] = g.x; t[r][c4 + 1] = g.y; t[r][c4 + 2] = g.z; t[r][c4 + 3] = g.w;
    }
    __syncthreads();
    for (int idx = tid; idx < 64 * 8; idx += 256) {
        int n = idx >> 3, k8 = (idx & 7) * 8;
        float s = (n0 + n < qcols) ? C2_ : 1.0f;
        u16x8 p;
        #pragma unroll
        for (int u = 0; u < 8; u++) p[u] = f2b(t[k8 + u][n] * s);
        *(u16x8*)&Wt[(size_t)(n0 + n) * K + k0 + k8] = p;
    }
}

// ---------------------------------------------------------------------------
// GEMM 128x128 (BT form), BK=64 + XOR swizzle (verified R7). Used for the
// out-projection (grid 512: good fit).
// ---------------------------------------------------------------------------
template<int BF16OUT>
__global__ __launch_bounds__(256) void gemm_bt(const u16* __restrict__ A,
                                               const u16* __restrict__ Bt,
                                               const float* __restrict__ bias,
                                               void* __restrict__ Cout,
                                               int M, int Nn, int K) {
    __shared__ u16 at[128 * 64];
    __shared__ u16 bt[128 * 64];
    const int tid = threadIdx.x;
    const int lane = tid & 63, wave = tid >> 6;
    const int wr = wave >> 1, wc = wave & 1;
    const int mlane = lane & 15, quad = lane >> 4;
    const int id = blockIdx.x;
    const int mt = (id & 7) * 8 + ((id >> 3) & 7);
    const int nt = id >> 6;
    const int m0 = mt * 128, n0 = nt * 128;
    const int r = tid >> 3, kc = (tid & 7) * 8;
    const int kcs = kc ^ ((r & 7) * 8);

    f32x4 acc[4][4] = {};

    for (int k0 = 0; k0 < K; k0 += 64) {
        __syncthreads();
        #pragma unroll
        for (int i = 0; i < 4; i++) {
            gll16(&A [(size_t)(m0 + r + 32 * i) * K + k0 + kcs], &at[(r + 32 * i) * 64 + kc]);
            gll16(&Bt[(size_t)(n0 + r + 32 * i) * K + k0 + kcs], &bt[(r + 32 * i) * 64 + kc]);
        }
        __syncthreads();

        #pragma unroll
        for (int ks = 0; ks < 2; ks++) {
            bf16x8 af[4], bf[4];
            #pragma unroll
            for (int rt = 0; rt < 4; rt++) {
                int row = wr * 64 + rt * 16 + mlane;
                af[rt] = *(const bf16x8*)&at[row * 64 + ((ks * 32 + quad * 8) ^ ((row & 7) * 8))];
            }
            #pragma unroll
            for (int ct = 0; ct < 4; ct++) {
                int row = wc * 64 + ct * 16 + mlane;
                bf[ct] = *(const bf16x8*)&bt[row * 64 + ((ks * 32 + quad * 8) ^ ((row & 7) * 8))];
            }
            #pragma unroll
            for (int rt = 0; rt < 4; rt++)
                #pragma unroll
                for (int ct = 0; ct < 4; ct++)
                    acc[rt][ct] = __builtin_amdgcn_mfma_f32_16x16x32_bf16(af[rt], bf[ct], acc[rt][ct], 0, 0, 0);
        }
    }

    const int row0 = m0 + wr * 64 + quad * 4;
    const int col0 = n0 + wc * 64 + mlane;
    #pragma unroll
    for (int rt = 0; rt < 4; rt++)
        #pragma unroll
        for (int ct = 0; ct < 4; ct++) {
            int c = col0 + ct * 16;
            float bv = (!BF16OUT && bias != nullptr) ? bias[c] : 0.f;
            #pragma unroll
            for (int reg = 0; reg < 4; reg++) {
                int rr = row0 + rt * 16 + reg;
                float v = acc[rt][ct][reg] + bv;
                if (BF16OUT) ((u16*)Cout)[(size_t)rr * Nn + c] = f2b(v);
                else         ((float*)Cout)[(size_t)rr * Nn + c] = v;
            }
        }
}

// ---------------------------------------------------------------------------
// R17 (resubmitted with host-pass fix): 256x256 8-phase counted-vmcnt GEMM
// (bf16 out, no bias) for the QKV projection. See R9 derivation:
//  - 512 thr / 8 waves; BK=64; LDS 128KB = 2 dbuf x 2 halves x [128][64] x {A,B}.
//  - Phase p computes output QUADRANT (p>>1, p&1); halves needed
//    progressively P0:{A0,B0}, P1:+B1, P2:+A1, P3:none; stage order for
//    tile T+1 = A0,B0,B1,A1 (one per phase, into tile T-1's buffer).
//  - Counted waits (queue sim, steady state): vmcnt(4) at ends of P0/P1/P3,
//    never 0; each wait precedes a barrier (per-wave -> cross-wave).
//    Peeled last tile drains 4 -> 2 -> 0.
//  - Frag reuse: A P0->P1, B0 P0->P2, B1 P1->P3 (28 ds_reads/tile/wave).
//  - XOR LDS swizzle identical to R7-verified (pre-swizzled gll16 source).
// ---------------------------------------------------------------------------
#define STAGE_A8(buf_, h_, k0_) do { \
    const u16* s_ = &A[(size_t)(m0 + (h_) * 128 + sr) * K + (k0_) + kcs]; \
    gll16(s_, &at[buf_][h_][sr * 64 + kc]); \
    gll16(s_ + (size_t)64 * K, &at[buf_][h_][(sr + 64) * 64 + kc]); \
} while (0)

#define STAGE_B8(buf_, h_, k0_) do { \
    const u16* s_ = &Bt[(size_t)(n0 + (h_) * 128 + sr) * K + (k0_) + kcs]; \
    gll16(s_, &bt[buf_][h_][sr * 64 + kc]); \
    gll16(s_ + (size_t)64 * K, &bt[buf_][h_][(sr + 64) * 64 + kc]); \
} while (0)

#define READ_AF8(b_, h_) do { \
    _Pragma("unroll") \
    for (int mf = 0; mf < 4; ++mf) { \
        int row_ = wm * 64 + mf * 16 + mlane; int sw_ = (row_ & 7) * 8; \
        af[mf][0] = *(const bf16x8*)&at[b_][h_][row_ * 64 + ((quad * 8) ^ sw_)]; \
        af[mf][1] = *(const bf16x8*)&at[b_][h_][row_ * 64 + ((32 + quad * 8) ^ sw_)]; \
    } \
} while (0)

#define READ_BF8(dst_, b_, h_) do { \
    _Pragma("unroll") \
    for (int nf = 0; nf < 2; ++nf) { \
        int row_ = wn4 * 32 + nf * 16 + mlane; int sw_ = (row_ & 7) * 8; \
        dst_[nf][0] = *(const bf16x8*)&bt[b_][h_][row_ * 64 + ((quad * 8) ^ sw_)]; \
        dst_[nf][1] = *(const bf16x8*)&bt[b_][h_][row_ * 64 + ((32 + quad * 8) ^ sw_)]; \
    } \
} while (0)

#define MFMA_PHASE8(p_, BF_) do { \
    __builtin_amdgcn_s_setprio(1); \
    _Pragma("unroll") \
    for (int mf = 0; mf < 4; ++mf) \
        _Pragma("unroll") \
        for (int nf = 0; nf < 2; ++nf) { \
            acc[p_][mf][nf] = __builtin_amdgcn_mfma_f32_16x16x32_bf16(af[mf][0], BF_[nf][0], acc[p_][mf][nf], 0, 0, 0); \
            acc[p_][mf][nf] = __builtin_amdgcn_mfma_f32_16x16x32_bf16(af[mf][1], BF_[nf][1], acc[p_][mf][nf], 0, 0, 0); \
        } \
    __builtin_amdgcn_s_setprio(0); \
} while (0)

#define VMWAIT8(n_) do { \
    asm volatile("s_waitcnt vmcnt(" #n_ ")" ::: "memory"); \
    __builtin_amdgcn_sched_barrier(0); \
} while (0)

__global__ __launch_bounds__(512, 2) void gemm_bt8(const u16* __restrict__ A,
                                                   const u16* __restrict__ Bt,
                                                   u16* __restrict__ Cout,
                                                   int M, int Nn, int K) {
    __shared__ u16 at[2][2][128 * 64];
    __shared__ u16 bt[2][2][128 * 64];
    const int tid = threadIdx.x;
    const int lane = tid & 63, wave = tid >> 6;
    const int wm = wave >> 2, wn4 = wave & 3;        // wave coords within a 128x128 quadrant
    const int mlane = lane & 15, quad = lane >> 4;
    const int ntx = Nn >> 8;
    const int nblk = (M >> 8) * ntx;
    const int id = blockIdx.x;
    const int v = (id & 7) * (nblk >> 3) + (id >> 3);   // XCD-bijective (nblk%8==0)
    const int mt = v / ntx, nt = v - mt * ntx;
    const int m0 = mt * 256, n0 = nt * 256;
    const int sr = tid >> 3, kc = (tid & 7) * 8;        // staging row 0..63, col chunk
    const int kcs = kc ^ ((sr & 7) * 8);                // pre-swizzled source col

    f32x4 acc[4][4][2] = {};    // [quadrant][mf][nf]
    bf16x8 af[4][2], bf0[2][2], bf1[2][2];

    const int NT = K >> 6;      // K-tiles

    // prologue: stage tile 0 -> buf0 (order A0, B0, B1, A1), guard P0
    STAGE_A8(0, 0, 0); STAGE_B8(0, 0, 0); STAGE_B8(0, 1, 0); STAGE_A8(0, 1, 0);
    VMWAIT8(4);                         // A0,B0 of tile 0 landed (own share)
    __builtin_amdgcn_s_barrier();       // -> landed for everyone

    for (int t = 0; t < NT - 1; ++t) {
        const int b = t & 1, nb = b ^ 1;
        const int kn = (t + 1) << 6;

        // ---- P0: quadrant (0,0) — A-half0 x B-half0 ----
        READ_AF8(b, 0);
        READ_BF8(bf0, b, 0);
        STAGE_A8(nb, 0, kn);
        __builtin_amdgcn_s_barrier();
        MFMA_PHASE8(0, bf0);
        VMWAIT8(4);                     // tile t's B1 landed (guards P1 reads)
        __builtin_amdgcn_s_barrier();

        // ---- P1: quadrant (0,1) — A-half0 (reused) x B-half1 ----
        READ_BF8(bf1, b, 1);
        STAGE_B8(nb, 0, kn);
        __builtin_amdgcn_s_barrier();
        MFMA_PHASE8(1, bf1);
        VMWAIT8(4);                     // tile t's A1 landed (guards P2 reads)
        __builtin_amdgcn_s_barrier();

        // ---- P2: quadrant (1,0) — A-half1 x B-half0 (reused) ----
        READ_AF8(b, 1);
        STAGE_B8(nb, 1, kn);
        __builtin_amdgcn_s_barrier();
        MFMA_PHASE8(2, bf0);
        __builtin_amdgcn_s_barrier();   // no wait: P3 reads nothing

        // ---- P3: quadrant (1,1) — A-half1 (reused) x B-half1 (reused) ----
        STAGE_A8(nb, 1, kn);
        __builtin_amdgcn_s_barrier();
        MFMA_PHASE8(3, bf1);
        VMWAIT8(4);                     // tile t+1's A0,B0 landed (guards next P0)
        __builtin_amdgcn_s_barrier();
    }

    // ---- peeled last tile (no staging): drain ladder 4 -> 2 -> 0 ----
    {
        const int b = (NT - 1) & 1;
        READ_AF8(b, 0);
        READ_BF8(bf0, b, 0);
        __builtin_amdgcn_s_barrier();
        MFMA_PHASE8(0, bf0);
        VMWAIT8(2);                     // B1 landed
        __builtin_amdgcn_s_barrier();

        READ_BF8(bf1, b, 1);
        __builtin_amdgcn_s_barrier();
        MFMA_PHASE8(1, bf1);
        VMWAIT8(0);                     // A1 landed (tail only)
        __builtin_amdgcn_s_barrier();

        READ_AF8(b, 1);
        __builtin_amdgcn_s_barrier();
        MFMA_PHASE8(2, bf0);
        __builtin_amdgcn_s_barrier();
        MFMA_PHASE8(3, bf1);
    }

    // epilogue: row = m0 + rh*128 + wm*64 + mf*16 + quad*4 + reg
    //           col = n0 + ch*128 + wn4*32 + nf*16 + mlane
    #pragma unroll
    for (int p = 0; p < 4; ++p) {
        const int rbase = m0 + (p >> 1) * 128 + wm * 64 + quad * 4;
        const int cbase = n0 + (p & 1) * 128 + wn4 * 32 + mlane;
        #pragma unroll
        for (int mf = 0; mf < 4; ++mf)
            #pragma unroll
            for (int nf = 0; nf < 2; ++nf)
                #pragma unroll
                for (int reg = 0; reg < 4; ++reg)
                    Cout[(size_t)(rbase + mf * 16 + reg) * Nn + cbase + nf * 16] = f2b(acc[p][mf][nf][reg]);
    }
}

// ---------------------------------------------------------------------------
// FUSED stats + V-transpose (unchanged).
// ---------------------------------------------------------------------------
__global__ __launch_bounds__(256) void attn_stats_vt(const u16* __restrict__ qkvb,
                                                     u16* __restrict__ vT) {
    __shared__ u16 kt[64 * 72];
    __shared__ u16 qt[4][64 * 72];
    __shared__ float red[4][64];
    __shared__ float li[64];

    const int tid = threadIdx.x;
    const int lane = tid & 63, wave = tid >> 6;
    const int mlane = lane & 15, quad = lane >> 4;
    const int id = blockIdx.x;
    const int bh = (id & 7) * 8 + ((id >> 3) & 7);
    const int b = bh >> 4, h = bh & 15;
    const int j0 = (id >> 6) * 64;

    const u16* qbase = qkvb + (size_t)b * N_ * RS_ + h * DH_;
    const u16* kbase = qbase + HID_;
    const u16* vbase = qbase + 2 * HID_;

    for (int idx = tid; idx < 512; idx += 256) {
        int r = idx >> 3, d8 = (idx & 7) * 8;
        *(u16x8*)&kt[r * 72 + d8] = *(const u16x8*)&kbase[(size_t)(j0 + r) * RS_ + d8];
    }
    __syncthreads();

    bf16x8 kf[4][2];
    #pragma unroll
    for (int t = 0; t < 4; t++)
        #pragma unroll
        for (int ks = 0; ks < 2; ks++)
            kf[t][ks] = *(const bf16x8*)&kt[(t * 16 + mlane) * 72 + ks * 32 + quad * 8];

    f32x4 acc[4] = {};
    u16* qw = &qt[wave][0];

    const int prr = lane >> 3, pd8 = (lane & 7) * 8;
    u16x8 pq[8];
    #pragma unroll
    for (int t = 0; t < 8; t++)
        pq[t] = *(const u16x8*)&qbase[(size_t)(wave * 64 + t * 8 + prr) * RS_ + pd8];

    for (int i0 = wave * 64; i0 < N_; i0 += 256) {
        #pragma unroll
        for (int t = 0; t < 8; t++)
            *(u16x8*)&qw[(t * 8 + prr) * 72 + pd8] = pq[t];
        int in = i0 + 256;
        if (in < N_) {
            #pragma unroll
            for (int t = 0; t < 8; t++)
                pq[t] = *(const u16x8*)&qbase[(size_t)(in + t * 8 + prr) * RS_ + pd8];
        }
        #pragma unroll
        for (int q4 = 0; q4 < 4; q4++) {
            bf16x8 bq0 = *(const bf16x8*)&qw[(q4 * 16 + mlane) * 72 + quad * 8];
            bf16x8 bq1 = *(const bf16x8*)&qw[(q4 * 16 + mlane) * 72 + 32 + quad * 8];
            #pragma unroll
            for (int t = 0; t < 4; t++) {
                f32x4 z = {0.f, 0.f, 0.f, 0.f};
                z = __builtin_amdgcn_mfma_f32_16x16x32_bf16(kf[t][0], bq0, z, 0, 0, 0);
                z = __builtin_amdgcn_mfma_f32_16x16x32_bf16(kf[t][1], bq1, z, 0, 0, 0);
                #pragma unroll
                for (int reg = 0; reg < 4; reg++)
                    acc[t][reg] += __builtin_amdgcn_exp2f(z[reg]);
            }
        }
    }

    #pragma unroll
    for (int t = 0; t < 4; t++)
        #pragma unroll
        for (int reg = 0; reg < 4; reg++) {
            float v = acc[t][reg];
            v += __shfl_xor(v, 1, 64);
            v += __shfl_xor(v, 2, 64);
            v += __shfl_xor(v, 4, 64);
            v += __shfl_xor(v, 8, 64);
            if (mlane == 0) red[wave][t * 16 + quad * 4 + reg] = v;
        }
    __syncthreads();
    if (tid < 64) {
        float l = red[0][tid] + red[1][tid] + red[2][tid] + red[3][tid];
        li[tid] = 1.0f / l;
    }

    for (int idx = tid; idx < 512; idx += 256) {
        int r = idx >> 3, d8 = (idx & 7) * 8;
        *(u16x8*)&kt[r * 72 + d8] = *(const u16x8*)&vbase[(size_t)(j0 + r) * RS_ + d8];
    }
    __syncthreads();
    {
        int d = tid >> 2, j16 = (tid & 3) * 16;
        u16x8 p0, p1;
        #pragma unroll
        for (int u = 0; u < 8; u++) {
            p0[u] = f2b(b2f(kt[(j16 + u) * 72 + d]) * li[j16 + u]);
            p1[u] = f2b(b2f(kt[(j16 + 8 + u) * 72 + d]) * li[j16 + 8 + u]);
        }
        size_t o = ((size_t)bh * DH_ + d) * N_ + j0 + j16;
        *(u16x8*)&vT[o] = p0;
        *(u16x8*)&vT[o + 8] = p1;
    }
}

// ---------------------------------------------------------------------------
// Apply (unchanged R16 structure: 256 q/block, 8 waves, K/V dbuf, setprio,
// XCD-bijective swizzle). Structural plateau ~77us (R6/R8 evidence).
// ---------------------------------------------------------------------------
__global__ __launch_bounds__(512) void attn_apply(const u16* __restrict__ qkvb,
                                                  const u16* __restrict__ vT,
                                                  u16* __restrict__ yb) {
    __shared__ u16 S[256 * 72];

    const int tid = threadIdx.x;
    const int lane = tid & 63, wave = tid >> 6;
    const int m31 = lane & 31, half = lane >> 5;

    const int id = blockIdx.x;
    const int v = (id & 7) * 64 + (id >> 3);
    const int bh = v >> 3, b = bh >> 4, h = bh & 15;
    const int i0 = (v & 7) * 256;

    const u16* qbase = qkvb + (size_t)b * N_ * RS_ + h * DH_;
    const u16* kbase = qbase + HID_;
    const u16* vbase = vT + (size_t)bh * DH_ * N_;

    for (int idx = tid; idx < 2048; idx += 512) {
        int r = idx >> 3, d8 = (idx & 7) * 8;
        *(u16x8*)&S[r * 72 + d8] = *(const u16x8*)&qbase[(size_t)(i0 + r) * RS_ + d8];
    }
    __syncthreads();

    bf16x8 qf[4];
    #pragma unroll
    for (int ks = 0; ks < 4; ks++)
        qf[ks] = *(const bf16x8*)&S[(wave * 32 + m31) * 72 + ks * 16 + half * 8];

    const int pr = tid >> 3, pc8 = (tid & 7) * 8;
    u16x8 pk, pv;
    pk = *(const u16x8*)&kbase[(size_t)pr * RS_ + pc8];
    pv = *(const u16x8*)&vbase[(size_t)pr * N_ + pc8];

    __syncthreads();

    f32x16 yacc[2] = {};

    int cur = 0;
    for (int j0 = 0; j0 < N_; j0 += 64, cur ^= 1) {
        u16* Sb = &S[cur * 128 * 72];
        *(u16x8*)&Sb[pr * 72 + pc8]        = pk;
        *(u16x8*)&Sb[(pr + 64) * 72 + pc8] = pv;
        __syncthreads();

        int jn = j0 + 64;
        if (jn < N_) {
            pk = *(const u16x8*)&kbase[(size_t)(jn + pr) * RS_ + pc8];
            pv = *(const u16x8*)&vbase[(size_t)pr * N_ + jn + pc8];
        }

        bf16x8 pa[4];
        #pragma unroll
        for (int kt = 0; kt < 2; kt++) {
            bf16x8 ka[4];
            #pragma unroll
            for (int ks = 0; ks < 4; ks++)
                ka[ks] = *(const bf16x8*)&Sb[(kt * 32 + m31) * 72 + ks * 16 + half * 8];

            f32x16 sc = {};
            __builtin_amdgcn_s_setprio(1);
            #pragma unroll
            for (int ks = 0; ks < 4; ks++)
                sc = __builtin_amdgcn_mfma_f32_32x32x16_bf16(ka[ks], qf[ks], sc, 0, 0, 0);
            __builtin_amdgcn_s_setprio(0);

            u32 P[4][2];
            #pragma unroll
            for (int rb = 0; rb < 4; rb++)
                #pragma unroll
                for (int pp = 0; pp < 2; pp++) {
                    float e0 = __builtin_amdgcn_exp2f(sc[4 * rb + 2 * pp]);
                    float e1 = __builtin_amdgcn_exp2f(sc[4 * rb + 2 * pp + 1]);
                    P[rb][pp] = pack2bf(e0, e1);
                }
            #pragma unroll
            for (int ksl = 0; ksl < 2; ksl++) {
                pl32swap(P[2 * ksl][0], P[2 * ksl + 1][0]);
                pl32swap(P[2 * ksl][1], P[2 * ksl + 1][1]);
                union { u32 u[4]; bf16x8 v; } cv;
                cv.u[0] = P[2 * ksl][0];
                cv.u[1] = P[2 * ksl][1];
                cv.u[2] = P[2 * ksl + 1][0];
                cv.u[3] = P[2 * ksl + 1][1];
                pa[2 * kt + ksl] = cv.v;
            }
        }

        __builtin_amdgcn_s_setprio(1);
        #pragma unroll
        for (int ks16 = 0; ks16 < 4; ks16++) {
            bf16x8 vb0 = *(const bf16x8*)&Sb[(64 + m31) * 72 + ks16 * 16 + half * 8];
            bf16x8 vb1 = *(const bf16x8*)&Sb[(96 + m31) * 72 + ks16 * 16 + half * 8];
            yacc[0] = __builtin_amdgcn_mfma_f32_32x32x16_bf16(pa[ks16], vb0, yacc[0], 0, 0, 0);
            yacc[1] = __builtin_amdgcn_mfma_f32_32x32x16_bf16(pa[ks16], vb1, yacc[1], 0, 0, 0);
        }
        __builtin_amdgcn_s_setprio(0);
    }

    #pragma unroll
    for (int dt = 0; dt < 2; dt++)
        #pragma unroll
        for (int reg = 0; reg < 16; reg++) {
            int q = i0 + wave * 32 + (reg & 3) + 8 * (reg >> 2) + 4 * half;
            yb[((size_t)b * N_ + q) * HID_ + h * DH_ + dt * 32 + m31] = f2b(yacc[dt][reg]);
        }
}

// ---------------------------------------------------------------------------
extern "C" void kernel_launch(void* const* d_in, const int* in_sizes, int n_in,
                              void* d_out, int out_size, void* d_ws, size_t ws_size,
                              hipStream_t stream) {
    (void)in_sizes; (void)n_in; (void)out_size; (void)ws_size;

    const float* x     = (const float*)d_in[0];
    const float* w_qkv = (const float*)d_in[1];
    const float* w_out = (const float*)d_in[2];
    const float* b_out = (const float*)d_in[3];

    u16* xb    = (u16*)d_ws;                          // [8192][1024]
    u16* wqkvT = xb    + (size_t)8192 * 1024;         // [3072][1024]
    u16* woutT = wqkvT + (size_t)3072 * 1024;         // [1024][1024]
    u16* qkvb  = woutT + (size_t)1024 * 1024;         // [8192][3072]
    u16* vTb   = qkvb  + (size_t)8192 * 3072;         // [64][64][2048]
    u16* yb    = vTb   + (size_t)64 * 64 * 2048;      // [8192][1024]

    cast_bf16<<<4096, 256, 0, stream>>>(x, xb, 8192 * 1024);
    transpose_cast<<<dim3(3072 / 64, 1024 / 64), 256, 0, stream>>>(w_qkv, wqkvT, 1024, 3072, HID_);
    transpose_cast<<<dim3(1024 / 64, 1024 / 64), 256, 0, stream>>>(w_out, woutT, 1024, 1024, 0);

    // R17: 8-phase 256^2 counted-vmcnt GEMM for QKV. grid = 32x12 = 384.
    gemm_bt8<<<384, 512, 0, stream>>>(xb, wqkvT, qkvb, 8192, 3072, 1024);

    // fused stats + V-transpose: grid = 32 j-tiles * 64 heads, XCD-swizzled
    attn_stats_vt<<<32 * 64, 256, 0, stream>>>(qkvb, vTb);

    // R16 shape: 256 q/block, 8 waves (512 thr), 1-D grid 512, XCD swizzle
    attn_apply<<<512, 512, 0, stream>>>(qkvb, vTb, yb);

    // out-projection: verified 128^2 BK=64 kernel (grid 512, good fit)
    gemm_bt<0><<<64 * 8, 256, 0, stream>>>(
        yb, woutT, b_out, d_out, 8192, 1024, 1024);
}

// Round 11
// 321.294 us; speedup vs baseline: 1.0242x; 1.0002x over previous
//
#include <hip/hip_runtime.h>
#include <math.h>
#include <stdint.h>

#define B_    4
#define N_    2048
#define DIM_  1024
#define H_    16
#define DH_   64
#define HID_  1024
#define RS_   3072          // qkv row stride (3*HID)
#define C2_   0.1803368801111204f   // (1/sqrt(64)) * log2(e), folded into Q columns of w_qkv

typedef unsigned short u16;
typedef unsigned int   u32;
typedef short  bf16x8 __attribute__((ext_vector_type(8)));   // 8 bf16 = 4 VGPRs (MFMA A/B frag)
typedef u16    u16x8  __attribute__((ext_vector_type(8)));   // 16B vector for bf16 data movement
typedef float  f32x4  __attribute__((ext_vector_type(4)));   // 16x16 MFMA C/D frag
typedef float  f32x16 __attribute__((ext_vector_type(16)));  // 32x32 MFMA C/D frag
typedef unsigned int u32x2 __attribute__((ext_vector_type(2)));

__device__ inline u16 f2b(float x) {   // fp32 -> bf16, round-to-nearest-even
    u32 u = __float_as_uint(x);
    return (u16)((u + 0x7fffu + ((u >> 16) & 1u)) >> 16);
}
__device__ inline float b2f(u16 x) {
    return __uint_as_float((u32)x << 16);
}

// pack two fp32 -> two bf16 (round-half-up). KNOWN-GOOD (R3).
__device__ inline u32 pack2bf(float f0, float f1) {
    u32 u0 = __float_as_uint(f0) + 0x8000u;
    u32 u1 = __float_as_uint(f1) + 0x8000u;
    return __builtin_amdgcn_perm(u1, u0, 0x07060302u);
}

// v_permlane32_swap_b32: vdst.row[1] <-> src.row[0]. VERIFIED R3.
__device__ inline void pl32swap(u32 &a, u32 &b) {
#if __has_builtin(__builtin_amdgcn_permlane32_swap)
    u32x2 r = __builtin_amdgcn_permlane32_swap(a, b, false, false);
    a = r[0]; b = r[1];
#else
    asm("v_permlane32_swap_b32 %0, %1" : "+v"(a), "+v"(b));
#endif
}

// gll16: declared for both passes (R10 fix); device builtin, host-parse fallback.
typedef const __attribute__((address_space(1))) u32* gas_ptr;
typedef __attribute__((address_space(3))) u32* las_ptr;
__device__ inline void gll16(const void* g, void* l) {
#if defined(__HIP_DEVICE_COMPILE__) && __has_builtin(__builtin_amdgcn_global_load_lds)
    __builtin_amdgcn_global_load_lds((gas_ptr)g, (las_ptr)l, 16, 0, 0);
#else
    *(u16x8*)l = *(const u16x8*)g;
#endif
}

// ---------------------------------------------------------------------------
// R18: PREP — fused {x cast} + {w_qkv transpose} + {w_out transpose} in one
// launch (they are mutually independent; all feed gemm8). 7 -> 5 kernel
// launches total. Grid partition: [0,4096) cast, [4096,4864) w_qkv 48x16,
// [4864,5120) w_out 16x16. Bodies identical to the verified R0 kernels.
// ---------------------------------------------------------------------------
__global__ __launch_bounds__(256) void prep(const float* __restrict__ x, u16* __restrict__ xb,
                                            const float* __restrict__ w_qkv, u16* __restrict__ wqkvT,
                                            const float* __restrict__ w_out, u16* __restrict__ woutT) {
    const int blk = blockIdx.x;
    const int tid = threadIdx.x;

    if (blk < 4096) {   // ---- cast x -> bf16, 8 elems/thread ----
        int i = (blk * 256 + tid) * 8;
        float4 a = *(const float4*)&x[i];
        float4 b = *(const float4*)&x[i + 4];
        u16x8 p;
        p[0] = f2b(a.x); p[1] = f2b(a.y); p[2] = f2b(a.z); p[3] = f2b(a.w);
        p[4] = f2b(b.x); p[5] = f2b(b.y); p[6] = f2b(b.z); p[7] = f2b(b.w);
        *(u16x8*)&xb[i] = p;
        return;
    }

    // ---- transpose+cast a 64x64 tile of one of the two weight matrices ----
    __shared__ float t[64][65];
    const float* W; u16* Wt; int K, Nn, qcols, bx, by;
    if (blk < 4096 + 768) {
        int r = blk - 4096; W = w_qkv; Wt = wqkvT; K = 1024; Nn = 3072; qcols = HID_;
        bx = r % 48; by = r / 48;
    } else {
        int r = blk - 4864; W = w_out; Wt = woutT; K = 1024; Nn = 1024; qcols = 0;
        bx = r % 16; by = r / 16;
    }
    const int k0 = by * 64, n0 = bx * 64;
    for (int idx = tid; idx < 64 * 16; idx += 256) {
        int r = idx >> 4, c4 = (idx & 15) * 4;
        float4 g = *(const float4*)&W[(size_t)(k0 + r) * Nn + n0 + c4];
        t[r][c4] = g.x; t[r][c4 + 1] = g.y; t[r][c4 + 2] = g.z; t[r][c4 + 3] = g.w;
    }
    __syncthreads();
    for (int idx = tid; idx < 64 * 8; idx += 256) {
        int n = idx >> 3, k8 = (idx & 7) * 8;
        float s = (n0 + n < qcols) ? C2_ : 1.0f;
        u16x8 p;
        #pragma unroll
        for (int u = 0; u < 8; u++) p[u] = f2b(t[k8 + u][n] * s);
        *(u16x8*)&Wt[(size_t)(n0 + n) * K + k0 + k8] = p;
    }
}

// ---------------------------------------------------------------------------
// GEMM 128x128 (BT form), BK=64 + XOR swizzle (verified R7). Out-projection.
// ---------------------------------------------------------------------------
template<int BF16OUT>
__global__ __launch_bounds__(256) void gemm_bt(const u16* __restrict__ A,
                                               const u16* __restrict__ Bt,
                                               const float* __restrict__ bias,
                                               void* __restrict__ Cout,
                                               int M, int Nn, int K) {
    __shared__ u16 at[128 * 64];
    __shared__ u16 bt[128 * 64];
    const int tid = threadIdx.x;
    const int lane = tid & 63, wave = tid >> 6;
    const int wr = wave >> 1, wc = wave & 1;
    const int mlane = lane & 15, quad = lane >> 4;
    const int id = blockIdx.x;
    const int mt = (id & 7) * 8 + ((id >> 3) & 7);
    const int nt = id >> 6;
    const int m0 = mt * 128, n0 = nt * 128;
    const int r = tid >> 3, kc = (tid & 7) * 8;
    const int kcs = kc ^ ((r & 7) * 8);

    f32x4 acc[4][4] = {};

    for (int k0 = 0; k0 < K; k0 += 64) {
        __syncthreads();
        #pragma unroll
        for (int i = 0; i < 4; i++) {
            gll16(&A [(size_t)(m0 + r + 32 * i) * K + k0 + kcs], &at[(r + 32 * i) * 64 + kc]);
            gll16(&Bt[(size_t)(n0 + r + 32 * i) * K + k0 + kcs], &bt[(r + 32 * i) * 64 + kc]);
        }
        __syncthreads();

        #pragma unroll
        for (int ks = 0; ks < 2; ks++) {
            bf16x8 af[4], bf[4];
            #pragma unroll
            for (int rt = 0; rt < 4; rt++) {
                int row = wr * 64 + rt * 16 + mlane;
                af[rt] = *(const bf16x8*)&at[row * 64 + ((ks * 32 + quad * 8) ^ ((row & 7) * 8))];
            }
            #pragma unroll
            for (int ct = 0; ct < 4; ct++) {
                int row = wc * 64 + ct * 16 + mlane;
                bf[ct] = *(const bf16x8*)&bt[row * 64 + ((ks * 32 + quad * 8) ^ ((row & 7) * 8))];
            }
            #pragma unroll
            for (int rt = 0; rt < 4; rt++)
                #pragma unroll
                for (int ct = 0; ct < 4; ct++)
                    acc[rt][ct] = __builtin_amdgcn_mfma_f32_16x16x32_bf16(af[rt], bf[ct], acc[rt][ct], 0, 0, 0);
        }
    }

    const int row0 = m0 + wr * 64 + quad * 4;
    const int col0 = n0 + wc * 64 + mlane;
    #pragma unroll
    for (int rt = 0; rt < 4; rt++)
        #pragma unroll
        for (int ct = 0; ct < 4; ct++) {
            int c = col0 + ct * 16;
            float bv = (!BF16OUT && bias != nullptr) ? bias[c] : 0.f;
            #pragma unroll
            for (int reg = 0; reg < 4; reg++) {
                int rr = row0 + rt * 16 + reg;
                float v = acc[rt][ct][reg] + bv;
                if (BF16OUT) ((u16*)Cout)[(size_t)rr * Nn + c] = f2b(v);
                else         ((float*)Cout)[(size_t)rr * Nn + c] = v;
            }
        }
}

// ---------------------------------------------------------------------------
// R17 (verified R10, kept): 256x256 8-phase counted-vmcnt GEMM for QKV.
// ~1030-1100 TF realized incl. the 1.5-rounds grid-quantization tax.
// ---------------------------------------------------------------------------
#define STAGE_A8(buf_, h_, k0_) do { \
    const u16* s_ = &A[(size_t)(m0 + (h_) * 128 + sr) * K + (k0_) + kcs]; \
    gll16(s_, &at[buf_][h_][sr * 64 + kc]); \
    gll16(s_ + (size_t)64 * K, &at[buf_][h_][(sr + 64) * 64 + kc]); \
} while (0)

#define STAGE_B8(buf_, h_, k0_) do { \
    const u16* s_ = &Bt[(size_t)(n0 + (h_) * 128 + sr) * K + (k0_) + kcs]; \
    gll16(s_, &bt[buf_][h_][sr * 64 + kc]); \
    gll16(s_ + (size_t)64 * K, &bt[buf_][h_][(sr + 64) * 64 + kc]); \
} while (0)

#define READ_AF8(b_, h_) do { \
    _Pragma("unroll") \
    for (int mf = 0; mf < 4; ++mf) { \
        int row_ = wm * 64 + mf * 16 + mlane; int sw_ = (row_ & 7) * 8; \
        af[mf][0] = *(const bf16x8*)&at[b_][h_][row_ * 64 + ((quad * 8) ^ sw_)]; \
        af[mf][1] = *(const bf16x8*)&at[b_][h_][row_ * 64 + ((32 + quad * 8) ^ sw_)]; \
    } \
} while (0)

#define READ_BF8(dst_, b_, h_) do { \
    _Pragma("unroll") \
    for (int nf = 0; nf < 2; ++nf) { \
        int row_ = wn4 * 32 + nf * 16 + mlane; int sw_ = (row_ & 7) * 8; \
        dst_[nf][0] = *(const bf16x8*)&bt[b_][h_][row_ * 64 + ((quad * 8) ^ sw_)]; \
        dst_[nf][1] = *(const bf16x8*)&bt[b_][h_][row_ * 64 + ((32 + quad * 8) ^ sw_)]; \
    } \
} while (0)

#define MFMA_PHASE8(p_, BF_) do { \
    __builtin_amdgcn_s_setprio(1); \
    _Pragma("unroll") \
    for (int mf = 0; mf < 4; ++mf) \
        _Pragma("unroll") \
        for (int nf = 0; nf < 2; ++nf) { \
            acc[p_][mf][nf] = __builtin_amdgcn_mfma_f32_16x16x32_bf16(af[mf][0], BF_[nf][0], acc[p_][mf][nf], 0, 0, 0); \
            acc[p_][mf][nf] = __builtin_amdgcn_mfma_f32_16x16x32_bf16(af[mf][1], BF_[nf][1], acc[p_][mf][nf], 0, 0, 0); \
        } \
    __builtin_amdgcn_s_setprio(0); \
} while (0)

#define VMWAIT8(n_) do { \
    asm volatile("s_waitcnt vmcnt(" #n_ ")" ::: "memory"); \
    __builtin_amdgcn_sched_barrier(0); \
} while (0)

__global__ __launch_bounds__(512, 2) void gemm_bt8(const u16* __restrict__ A,
                                                   const u16* __restrict__ Bt,
                                                   u16* __restrict__ Cout,
                                                   int M, int Nn, int K) {
    __shared__ u16 at[2][2][128 * 64];
    __shared__ u16 bt[2][2][128 * 64];
    const int tid = threadIdx.x;
    const int lane = tid & 63, wave = tid >> 6;
    const int wm = wave >> 2, wn4 = wave & 3;
    const int mlane = lane & 15, quad = lane >> 4;
    const int ntx = Nn >> 8;
    const int nblk = (M >> 8) * ntx;
    const int id = blockIdx.x;
    const int v = (id & 7) * (nblk >> 3) + (id >> 3);
    const int mt = v / ntx, nt = v - mt * ntx;
    const int m0 = mt * 256, n0 = nt * 256;
    const int sr = tid >> 3, kc = (tid & 7) * 8;
    const int kcs = kc ^ ((sr & 7) * 8);

    f32x4 acc[4][4][2] = {};
    bf16x8 af[4][2], bf0[2][2], bf1[2][2];

    const int NT = K >> 6;

    STAGE_A8(0, 0, 0); STAGE_B8(0, 0, 0); STAGE_B8(0, 1, 0); STAGE_A8(0, 1, 0);
    VMWAIT8(4);
    __builtin_amdgcn_s_barrier();

    for (int t = 0; t < NT - 1; ++t) {
        const int b = t & 1, nb = b ^ 1;
        const int kn = (t + 1) << 6;

        READ_AF8(b, 0);
        READ_BF8(bf0, b, 0);
        STAGE_A8(nb, 0, kn);
        __builtin_amdgcn_s_barrier();
        MFMA_PHASE8(0, bf0);
        VMWAIT8(4);
        __builtin_amdgcn_s_barrier();

        READ_BF8(bf1, b, 1);
        STAGE_B8(nb, 0, kn);
        __builtin_amdgcn_s_barrier();
        MFMA_PHASE8(1, bf1);
        VMWAIT8(4);
        __builtin_amdgcn_s_barrier();

        READ_AF8(b, 1);
        STAGE_B8(nb, 1, kn);
        __builtin_amdgcn_s_barrier();
        MFMA_PHASE8(2, bf0);
        __builtin_amdgcn_s_barrier();

        STAGE_A8(nb, 1, kn);
        __builtin_amdgcn_s_barrier();
        MFMA_PHASE8(3, bf1);
        VMWAIT8(4);
        __builtin_amdgcn_s_barrier();
    }

    {
        const int b = (NT - 1) & 1;
        READ_AF8(b, 0);
        READ_BF8(bf0, b, 0);
        __builtin_amdgcn_s_barrier();
        MFMA_PHASE8(0, bf0);
        VMWAIT8(2);
        __builtin_amdgcn_s_barrier();

        READ_BF8(bf1, b, 1);
        __builtin_amdgcn_s_barrier();
        MFMA_PHASE8(1, bf1);
        VMWAIT8(0);
        __builtin_amdgcn_s_barrier();

        READ_AF8(b, 1);
        __builtin_amdgcn_s_barrier();
        MFMA_PHASE8(2, bf0);
        __builtin_amdgcn_s_barrier();
        MFMA_PHASE8(3, bf1);
    }

    #pragma unroll
    for (int p = 0; p < 4; ++p) {
        const int rbase = m0 + (p >> 1) * 128 + wm * 64 + quad * 4;
        const int cbase = n0 + (p & 1) * 128 + wn4 * 32 + mlane;
        #pragma unroll
        for (int mf = 0; mf < 4; ++mf)
            #pragma unroll
            for (int nf = 0; nf < 2; ++nf)
                #pragma unroll
                for (int reg = 0; reg < 4; ++reg)
                    Cout[(size_t)(rbase + mf * 16 + reg) * Nn + cbase + nf * 16] = f2b(acc[p][mf][nf][reg]);
    }
}

// ---------------------------------------------------------------------------
// FUSED stats + V-transpose (unchanged; Q working set 2MB/XCD is L2-fit).
// ---------------------------------------------------------------------------
__global__ __launch_bounds__(256) void attn_stats_vt(const u16* __restrict__ qkvb,
                                                     u16* __restrict__ vT) {
    __shared__ u16 kt[64 * 72];
    __shared__ u16 qt[4][64 * 72];
    __shared__ float red[4][64];
    __shared__ float li[64];

    const int tid = threadIdx.x;
    const int lane = tid & 63, wave = tid >> 6;
    const int mlane = lane & 15, quad = lane >> 4;
    const int id = blockIdx.x;
    const int bh = (id & 7) * 8 + ((id >> 3) & 7);
    const int b = bh >> 4, h = bh & 15;
    const int j0 = (id >> 6) * 64;

    const u16* qbase = qkvb + (size_t)b * N_ * RS_ + h * DH_;
    const u16* kbase = qbase + HID_;
    const u16* vbase = qbase + 2 * HID_;

    for (int idx = tid; idx < 512; idx += 256) {
        int r = idx >> 3, d8 = (idx & 7) * 8;
        *(u16x8*)&kt[r * 72 + d8] = *(const u16x8*)&kbase[(size_t)(j0 + r) * RS_ + d8];
    }
    __syncthreads();

    bf16x8 kf[4][2];
    #pragma unroll
    for (int t = 0; t < 4; t++)
        #pragma unroll
        for (int ks = 0; ks < 2; ks++)
            kf[t][ks] = *(const bf16x8*)&kt[(t * 16 + mlane) * 72 + ks * 32 + quad * 8];

    f32x4 acc[4] = {};
    u16* qw = &qt[wave][0];

    const int prr = lane >> 3, pd8 = (lane & 7) * 8;
    u16x8 pq[8];
    #pragma unroll
    for (int t = 0; t < 8; t++)
        pq[t] = *(const u16x8*)&qbase[(size_t)(wave * 64 + t * 8 + prr) * RS_ + pd8];

    for (int i0 = wave * 64; i0 < N_; i0 += 256) {
        #pragma unroll
        for (int t = 0; t < 8; t++)
            *(u16x8*)&qw[(t * 8 + prr) * 72 + pd8] = pq[t];
        int in = i0 + 256;
        if (in < N_) {
            #pragma unroll
            for (int t = 0; t < 8; t++)
                pq[t] = *(const u16x8*)&qbase[(size_t)(in + t * 8 + prr) * RS_ + pd8];
        }
        #pragma unroll
        for (int q4 = 0; q4 < 4; q4++) {
            bf16x8 bq0 = *(const bf16x8*)&qw[(q4 * 16 + mlane) * 72 + quad * 8];
            bf16x8 bq1 = *(const bf16x8*)&qw[(q4 * 16 + mlane) * 72 + 32 + quad * 8];
            #pragma unroll
            for (int t = 0; t < 4; t++) {
                f32x4 z = {0.f, 0.f, 0.f, 0.f};
                z = __builtin_amdgcn_mfma_f32_16x16x32_bf16(kf[t][0], bq0, z, 0, 0, 0);
                z = __builtin_amdgcn_mfma_f32_16x16x32_bf16(kf[t][1], bq1, z, 0, 0, 0);
                #pragma unroll
                for (int reg = 0; reg < 4; reg++)
                    acc[t][reg] += __builtin_amdgcn_exp2f(z[reg]);
            }
        }
    }

    #pragma unroll
    for (int t = 0; t < 4; t++)
        #pragma unroll
        for (int reg = 0; reg < 4; reg++) {
            float v = acc[t][reg];
            v += __shfl_xor(v, 1, 64);
            v += __shfl_xor(v, 2, 64);
            v += __shfl_xor(v, 4, 64);
            v += __shfl_xor(v, 8, 64);
            if (mlane == 0) red[wave][t * 16 + quad * 4 + reg] = v;
        }
    __syncthreads();
    if (tid < 64) {
        float l = red[0][tid] + red[1][tid] + red[2][tid] + red[3][tid];
        li[tid] = 1.0f / l;
    }

    for (int idx = tid; idx < 512; idx += 256) {
        int r = idx >> 3, d8 = (idx & 7) * 8;
        *(u16x8*)&kt[r * 72 + d8] = *(const u16x8*)&vbase[(size_t)(j0 + r) * RS_ + d8];
    }
    __syncthreads();
    {
        int d = tid >> 2, j16 = (tid & 3) * 16;
        u16x8 p0, p1;
        #pragma unroll
        for (int u = 0; u < 8; u++) {
            p0[u] = f2b(b2f(kt[(j16 + u) * 72 + d]) * li[j16 + u]);
            p1[u] = f2b(b2f(kt[(j16 + 8 + u) * 72 + d]) * li[j16 + 8 + u]);
        }
        size_t o = ((size_t)bh * DH_ + d) * N_ + j0 + j16;
        *(u16x8*)&vT[o] = p0;
        *(u16x8*)&vT[o + 8] = p1;
    }
}

// ---------------------------------------------------------------------------
// Apply (unchanged R16: 256 q/block, 8 waves, K/V dbuf, setprio, XCD swizzle).
// Structural plateau ~75-77us (R6/R8: dbuf, setprio, swizzle all neutral on
// time; LDS-read volume per query is invariant at 16 waves/CU occupancy).
// ---------------------------------------------------------------------------
__global__ __launch_bounds__(512) void attn_apply(const u16* __restrict__ qkvb,
                                                  const u16* __restrict__ vT,
                                                  u16* __restrict__ yb) {
    __shared__ u16 S[256 * 72];

    const int tid = threadIdx.x;
    const int lane = tid & 63, wave = tid >> 6;
    const int m31 = lane & 31, half = lane >> 5;

    const int id = blockIdx.x;
    const int v = (id & 7) * 64 + (id >> 3);
    const int bh = v >> 3, b = bh >> 4, h = bh & 15;
    const int i0 = (v & 7) * 256;

    const u16* qbase = qkvb + (size_t)b * N_ * RS_ + h * DH_;
    const u16* kbase = qbase + HID_;
    const u16* vbase = vT + (size_t)bh * DH_ * N_;

    for (int idx = tid; idx < 2048; idx += 512) {
        int r = idx >> 3, d8 = (idx & 7) * 8;
        *(u16x8*)&S[r * 72 + d8] = *(const u16x8*)&qbase[(size_t)(i0 + r) * RS_ + d8];
    }
    __syncthreads();

    bf16x8 qf[4];
    #pragma unroll
    for (int ks = 0; ks < 4; ks++)
        qf[ks] = *(const bf16x8*)&S[(wave * 32 + m31) * 72 + ks * 16 + half * 8];

    const int pr = tid >> 3, pc8 = (tid & 7) * 8;
    u16x8 pk, pv;
    pk = *(const u16x8*)&kbase[(size_t)pr * RS_ + pc8];
    pv = *(const u16x8*)&vbase[(size_t)pr * N_ + pc8];

    __syncthreads();

    f32x16 yacc[2] = {};

    int cur = 0;
    for (int j0 = 0; j0 < N_; j0 += 64, cur ^= 1) {
        u16* Sb = &S[cur * 128 * 72];
        *(u16x8*)&Sb[pr * 72 + pc8]        = pk;
        *(u16x8*)&Sb[(pr + 64) * 72 + pc8] = pv;
        __syncthreads();

        int jn = j0 + 64;
        if (jn < N_) {
            pk = *(const u16x8*)&kbase[(size_t)(jn + pr) * RS_ + pc8];
            pv = *(const u16x8*)&vbase[(size_t)pr * N_ + jn + pc8];
        }

        bf16x8 pa[4];
        #pragma unroll
        for (int kt = 0; kt < 2; kt++) {
            bf16x8 ka[4];
            #pragma unroll
            for (int ks = 0; ks < 4; ks++)
                ka[ks] = *(const bf16x8*)&Sb[(kt * 32 + m31) * 72 + ks * 16 + half * 8];

            f32x16 sc = {};
            __builtin_amdgcn_s_setprio(1);
            #pragma unroll
            for (int ks = 0; ks < 4; ks++)
                sc = __builtin_amdgcn_mfma_f32_32x32x16_bf16(ka[ks], qf[ks], sc, 0, 0, 0);
            __builtin_amdgcn_s_setprio(0);

            u32 P[4][2];
            #pragma unroll
            for (int rb = 0; rb < 4; rb++)
                #pragma unroll
                for (int pp = 0; pp < 2; pp++) {
                    float e0 = __builtin_amdgcn_exp2f(sc[4 * rb + 2 * pp]);
                    float e1 = __builtin_amdgcn_exp2f(sc[4 * rb + 2 * pp + 1]);
                    P[rb][pp] = pack2bf(e0, e1);
                }
            #pragma unroll
            for (int ksl = 0; ksl < 2; ksl++) {
                pl32swap(P[2 * ksl][0], P[2 * ksl + 1][0]);
                pl32swap(P[2 * ksl][1], P[2 * ksl + 1][1]);
                union { u32 u[4]; bf16x8 v; } cv;
                cv.u[0] = P[2 * ksl][0];
                cv.u[1] = P[2 * ksl][1];
                cv.u[2] = P[2 * ksl + 1][0];
                cv.u[3] = P[2 * ksl + 1][1];
                pa[2 * kt + ksl] = cv.v;
            }
        }

        __builtin_amdgcn_s_setprio(1);
        #pragma unroll
        for (int ks16 = 0; ks16 < 4; ks16++) {
            bf16x8 vb0 = *(const bf16x8*)&Sb[(64 + m31) * 72 + ks16 * 16 + half * 8];
            bf16x8 vb1 = *(const bf16x8*)&Sb[(96 + m31) * 72 + ks16 * 16 + half * 8];
            yacc[0] = __builtin_amdgcn_mfma_f32_32x32x16_bf16(pa[ks16], vb0, yacc[0], 0, 0, 0);
            yacc[1] = __builtin_amdgcn_mfma_f32_32x32x16_bf16(pa[ks16], vb1, yacc[1], 0, 0, 0);
        }
        __builtin_amdgcn_s_setprio(0);
    }

    #pragma unroll
    for (int dt = 0; dt < 2; dt++)
        #pragma unroll
        for (int reg = 0; reg < 16; reg++) {
            int q = i0 + wave * 32 + (reg & 3) + 8 * (reg >> 2) + 4 * half;
            yb[((size_t)b * N_ + q) * HID_ + h * DH_ + dt * 32 + m31] = f2b(yacc[dt][reg]);
        }
}

// ---------------------------------------------------------------------------
extern "C" void kernel_launch(void* const* d_in, const int* in_sizes, int n_in,
                              void* d_out, int out_size, void* d_ws, size_t ws_size,
                              hipStream_t stream) {
    (void)in_sizes; (void)n_in; (void)out_size; (void)ws_size;

    const float* x     = (const float*)d_in[0];
    const float* w_qkv = (const float*)d_in[1];
    const float* w_out = (const float*)d_in[2];
    const float* b_out = (const float*)d_in[3];

    u16* xb    = (u16*)d_ws;                          // [8192][1024]
    u16* wqkvT = xb    + (size_t)8192 * 1024;         // [3072][1024]
    u16* woutT = wqkvT + (size_t)3072 * 1024;         // [1024][1024]
    u16* qkvb  = woutT + (size_t)1024 * 1024;         // [8192][3072]
    u16* vTb   = qkvb  + (size_t)8192 * 3072;         // [64][64][2048]
    u16* yb    = vTb   + (size_t)64 * 64 * 2048;      // [8192][1024]

    // R18: single fused prep launch (cast + both weight transposes)
    prep<<<5120, 256, 0, stream>>>(x, xb, w_qkv, wqkvT, w_out, woutT);

    // 8-phase 256^2 counted-vmcnt GEMM for QKV. grid = 32x12 = 384.
    gemm_bt8<<<384, 512, 0, stream>>>(xb, wqkvT, qkvb, 8192, 3072, 1024);

    // fused stats + V-transpose: grid = 32 j-tiles * 64 heads, XCD-swizzled
    attn_stats_vt<<<32 * 64, 256, 0, stream>>>(qkvb, vTb);

    // attn apply: 256 q/block, 8 waves, 1-D grid 512, XCD swizzle
    attn_apply<<<512, 512, 0, stream>>>(qkvb, vTb, yb);

    // out-projection: verified 128^2 BK=64 kernel (grid 512, good fit)
    gemm_bt<0><<<64 * 8, 256, 0, stream>>>(
        yb, woutT, b_out, d_out, 8192, 1024, 1024);
}

// Round 12
// 304.136 us; speedup vs baseline: 1.0820x; 1.0564x over previous
//
#include <hip/hip_runtime.h>
#include <math.h>
#include <stdint.h>

#define B_    4
#define N_    2048
#define DIM_  1024
#define H_    16
#define DH_   64
#define HID_  1024
#define RS_   3072          // qkv row stride (3*HID)
#define C2_   0.1803368801111204f   // (1/sqrt(64)) * log2(e), folded into Q columns of w_qkv

typedef unsigned short u16;
typedef unsigned int   u32;
typedef short  bf16x8 __attribute__((ext_vector_type(8)));   // 8 bf16 = 4 VGPRs (MFMA A/B frag)
typedef u16    u16x8  __attribute__((ext_vector_type(8)));   // 16B vector for bf16 data movement
typedef float  f32x4  __attribute__((ext_vector_type(4)));   // 16x16 MFMA C/D frag
typedef float  f32x16 __attribute__((ext_vector_type(16)));  // 32x32 MFMA C/D frag
typedef unsigned int u32x2 __attribute__((ext_vector_type(2)));

__device__ inline u16 f2b(float x) {   // fp32 -> bf16, round-to-nearest-even
    u32 u = __float_as_uint(x);
    return (u16)((u + 0x7fffu + ((u >> 16) & 1u)) >> 16);
}
__device__ inline float b2f(u16 x) {
    return __uint_as_float((u32)x << 16);
}

// pack two fp32 -> two bf16 (round-half-up). KNOWN-GOOD (R3).
__device__ inline u32 pack2bf(float f0, float f1) {
    u32 u0 = __float_as_uint(f0) + 0x8000u;
    u32 u1 = __float_as_uint(f1) + 0x8000u;
    return __builtin_amdgcn_perm(u1, u0, 0x07060302u);
}

// v_permlane32_swap_b32: vdst.row[1] <-> src.row[0]. VERIFIED R3.
__device__ inline void pl32swap(u32 &a, u32 &b) {
#if __has_builtin(__builtin_amdgcn_permlane32_swap)
    u32x2 r = __builtin_amdgcn_permlane32_swap(a, b, false, false);
    a = r[0]; b = r[1];
#else
    asm("v_permlane32_swap_b32 %0, %1" : "+v"(a), "+v"(b));
#endif
}

// gll16: declared for both passes (R10 fix); device builtin, host-parse fallback.
typedef const __attribute__((address_space(1))) u32* gas_ptr;
typedef __attribute__((address_space(3))) u32* las_ptr;
__device__ inline void gll16(const void* g, void* l) {
#if defined(__HIP_DEVICE_COMPILE__) && __has_builtin(__builtin_amdgcn_global_load_lds)
    __builtin_amdgcn_global_load_lds((gas_ptr)g, (las_ptr)l, 16, 0, 0);
#else
    *(u16x8*)l = *(const u16x8*)g;
#endif
}

// ---------------------------------------------------------------------------
// PREP — fused {x cast} + {w_qkv transpose} + {w_out transpose} (R18, kept).
// ---------------------------------------------------------------------------
__global__ __launch_bounds__(256) void prep(const float* __restrict__ x, u16* __restrict__ xb,
                                            const float* __restrict__ w_qkv, u16* __restrict__ wqkvT,
                                            const float* __restrict__ w_out, u16* __restrict__ woutT) {
    const int blk = blockIdx.x;
    const int tid = threadIdx.x;

    if (blk < 4096) {   // ---- cast x -> bf16, 8 elems/thread ----
        int i = (blk * 256 + tid) * 8;
        float4 a = *(const float4*)&x[i];
        float4 b = *(const float4*)&x[i + 4];
        u16x8 p;
        p[0] = f2b(a.x); p[1] = f2b(a.y); p[2] = f2b(a.z); p[3] = f2b(a.w);
        p[4] = f2b(b.x); p[5] = f2b(b.y); p[6] = f2b(b.z); p[7] = f2b(b.w);
        *(u16x8*)&xb[i] = p;
        return;
    }

    // ---- transpose+cast a 64x64 tile of one of the two weight matrices ----
    __shared__ float t[64][65];
    const float* W; u16* Wt; int K, Nn, qcols, bx, by;
    if (blk < 4096 + 768) {
        int r = blk - 4096; W = w_qkv; Wt = wqkvT; K = 1024; Nn = 3072; qcols = HID_;
        bx = r % 48; by = r / 48;
    } else {
        int r = blk - 4864; W = w_out; Wt = woutT; K = 1024; Nn = 1024; qcols = 0;
        bx = r % 16; by = r / 16;
    }
    const int k0 = by * 64, n0 = bx * 64;
    for (int idx = tid; idx < 64 * 16; idx += 256) {
        int r = idx >> 4, c4 = (idx & 15) * 4;
        float4 g = *(const float4*)&W[(size_t)(k0 + r) * Nn + n0 + c4];
        t[r][c4] = g.x; t[r][c4 + 1] = g.y; t[r][c4 + 2] = g.z; t[r][c4 + 3] = g.w;
    }
    __syncthreads();
    for (int idx = tid; idx < 64 * 8; idx += 256) {
        int n = idx >> 3, k8 = (idx & 7) * 8;
        float s = (n0 + n < qcols) ? C2_ : 1.0f;
        u16x8 p;
        #pragma unroll
        for (int u = 0; u < 8; u++) p[u] = f2b(t[k8 + u][n] * s);
        *(u16x8*)&Wt[(size_t)(n0 + n) * K + k0 + k8] = p;
    }
}

// ---------------------------------------------------------------------------
// GEMM 128x128 (BT form), BK=64 + XOR swizzle (verified R7). Out-projection.
// ---------------------------------------------------------------------------
template<int BF16OUT>
__global__ __launch_bounds__(256) void gemm_bt(const u16* __restrict__ A,
                                               const u16* __restrict__ Bt,
                                               const float* __restrict__ bias,
                                               void* __restrict__ Cout,
                                               int M, int Nn, int K) {
    __shared__ u16 at[128 * 64];
    __shared__ u16 bt[128 * 64];
    const int tid = threadIdx.x;
    const int lane = tid & 63, wave = tid >> 6;
    const int wr = wave >> 1, wc = wave & 1;
    const int mlane = lane & 15, quad = lane >> 4;
    const int id = blockIdx.x;
    const int mt = (id & 7) * 8 + ((id >> 3) & 7);
    const int nt = id >> 6;
    const int m0 = mt * 128, n0 = nt * 128;
    const int r = tid >> 3, kc = (tid & 7) * 8;
    const int kcs = kc ^ ((r & 7) * 8);

    f32x4 acc[4][4] = {};

    for (int k0 = 0; k0 < K; k0 += 64) {
        __syncthreads();
        #pragma unroll
        for (int i = 0; i < 4; i++) {
            gll16(&A [(size_t)(m0 + r + 32 * i) * K + k0 + kcs], &at[(r + 32 * i) * 64 + kc]);
            gll16(&Bt[(size_t)(n0 + r + 32 * i) * K + k0 + kcs], &bt[(r + 32 * i) * 64 + kc]);
        }
        __syncthreads();

        #pragma unroll
        for (int ks = 0; ks < 2; ks++) {
            bf16x8 af[4], bf[4];
            #pragma unroll
            for (int rt = 0; rt < 4; rt++) {
                int row = wr * 64 + rt * 16 + mlane;
                af[rt] = *(const bf16x8*)&at[row * 64 + ((ks * 32 + quad * 8) ^ ((row & 7) * 8))];
            }
            #pragma unroll
            for (int ct = 0; ct < 4; ct++) {
                int row = wc * 64 + ct * 16 + mlane;
                bf[ct] = *(const bf16x8*)&bt[row * 64 + ((ks * 32 + quad * 8) ^ ((row & 7) * 8))];
            }
            #pragma unroll
            for (int rt = 0; rt < 4; rt++)
                #pragma unroll
                for (int ct = 0; ct < 4; ct++)
                    acc[rt][ct] = __builtin_amdgcn_mfma_f32_16x16x32_bf16(af[rt], bf[ct], acc[rt][ct], 0, 0, 0);
        }
    }

    const int row0 = m0 + wr * 64 + quad * 4;
    const int col0 = n0 + wc * 64 + mlane;
    #pragma unroll
    for (int rt = 0; rt < 4; rt++)
        #pragma unroll
        for (int ct = 0; ct < 4; ct++) {
            int c = col0 + ct * 16;
            float bv = (!BF16OUT && bias != nullptr) ? bias[c] : 0.f;
            #pragma unroll
            for (int reg = 0; reg < 4; reg++) {
                int rr = row0 + rt * 16 + reg;
                float v = acc[rt][ct][reg] + bv;
                if (BF16OUT) ((u16*)Cout)[(size_t)rr * Nn + c] = f2b(v);
                else         ((float*)Cout)[(size_t)rr * Nn + c] = v;
            }
        }
}

// ---------------------------------------------------------------------------
// R17 (verified R10): 256x256 8-phase counted-vmcnt GEMM for QKV.
// ---------------------------------------------------------------------------
#define STAGE_A8(buf_, h_, k0_) do { \
    const u16* s_ = &A[(size_t)(m0 + (h_) * 128 + sr) * K + (k0_) + kcs]; \
    gll16(s_, &at[buf_][h_][sr * 64 + kc]); \
    gll16(s_ + (size_t)64 * K, &at[buf_][h_][(sr + 64) * 64 + kc]); \
} while (0)

#define STAGE_B8(buf_, h_, k0_) do { \
    const u16* s_ = &Bt[(size_t)(n0 + (h_) * 128 + sr) * K + (k0_) + kcs]; \
    gll16(s_, &bt[buf_][h_][sr * 64 + kc]); \
    gll16(s_ + (size_t)64 * K, &bt[buf_][h_][(sr + 64) * 64 + kc]); \
} while (0)

#define READ_AF8(b_, h_) do { \
    _Pragma("unroll") \
    for (int mf = 0; mf < 4; ++mf) { \
        int row_ = wm * 64 + mf * 16 + mlane; int sw_ = (row_ & 7) * 8; \
        af[mf][0] = *(const bf16x8*)&at[b_][h_][row_ * 64 + ((quad * 8) ^ sw_)]; \
        af[mf][1] = *(const bf16x8*)&at[b_][h_][row_ * 64 + ((32 + quad * 8) ^ sw_)]; \
    } \
} while (0)

#define READ_BF8(dst_, b_, h_) do { \
    _Pragma("unroll") \
    for (int nf = 0; nf < 2; ++nf) { \
        int row_ = wn4 * 32 + nf * 16 + mlane; int sw_ = (row_ & 7) * 8; \
        dst_[nf][0] = *(const bf16x8*)&bt[b_][h_][row_ * 64 + ((quad * 8) ^ sw_)]; \
        dst_[nf][1] = *(const bf16x8*)&bt[b_][h_][row_ * 64 + ((32 + quad * 8) ^ sw_)]; \
    } \
} while (0)

#define MFMA_PHASE8(p_, BF_) do { \
    __builtin_amdgcn_s_setprio(1); \
    _Pragma("unroll") \
    for (int mf = 0; mf < 4; ++mf) \
        _Pragma("unroll") \
        for (int nf = 0; nf < 2; ++nf) { \
            acc[p_][mf][nf] = __builtin_amdgcn_mfma_f32_16x16x32_bf16(af[mf][0], BF_[nf][0], acc[p_][mf][nf], 0, 0, 0); \
            acc[p_][mf][nf] = __builtin_amdgcn_mfma_f32_16x16x32_bf16(af[mf][1], BF_[nf][1], acc[p_][mf][nf], 0, 0, 0); \
        } \
    __builtin_amdgcn_s_setprio(0); \
} while (0)

#define VMWAIT8(n_) do { \
    asm volatile("s_waitcnt vmcnt(" #n_ ")" ::: "memory"); \
    __builtin_amdgcn_sched_barrier(0); \
} while (0)

__global__ __launch_bounds__(512, 2) void gemm_bt8(const u16* __restrict__ A,
                                                   const u16* __restrict__ Bt,
                                                   u16* __restrict__ Cout,
                                                   int M, int Nn, int K) {
    __shared__ u16 at[2][2][128 * 64];
    __shared__ u16 bt[2][2][128 * 64];
    const int tid = threadIdx.x;
    const int lane = tid & 63, wave = tid >> 6;
    const int wm = wave >> 2, wn4 = wave & 3;
    const int mlane = lane & 15, quad = lane >> 4;
    const int ntx = Nn >> 8;
    const int nblk = (M >> 8) * ntx;
    const int id = blockIdx.x;
    const int v = (id & 7) * (nblk >> 3) + (id >> 3);
    const int mt = v / ntx, nt = v - mt * ntx;
    const int m0 = mt * 256, n0 = nt * 256;
    const int sr = tid >> 3, kc = (tid & 7) * 8;
    const int kcs = kc ^ ((sr & 7) * 8);

    f32x4 acc[4][4][2] = {};
    bf16x8 af[4][2], bf0[2][2], bf1[2][2];

    const int NT = K >> 6;

    STAGE_A8(0, 0, 0); STAGE_B8(0, 0, 0); STAGE_B8(0, 1, 0); STAGE_A8(0, 1, 0);
    VMWAIT8(4);
    __builtin_amdgcn_s_barrier();

    for (int t = 0; t < NT - 1; ++t) {
        const int b = t & 1, nb = b ^ 1;
        const int kn = (t + 1) << 6;

        READ_AF8(b, 0);
        READ_BF8(bf0, b, 0);
        STAGE_A8(nb, 0, kn);
        __builtin_amdgcn_s_barrier();
        MFMA_PHASE8(0, bf0);
        VMWAIT8(4);
        __builtin_amdgcn_s_barrier();

        READ_BF8(bf1, b, 1);
        STAGE_B8(nb, 0, kn);
        __builtin_amdgcn_s_barrier();
        MFMA_PHASE8(1, bf1);
        VMWAIT8(4);
        __builtin_amdgcn_s_barrier();

        READ_AF8(b, 1);
        STAGE_B8(nb, 1, kn);
        __builtin_amdgcn_s_barrier();
        MFMA_PHASE8(2, bf0);
        __builtin_amdgcn_s_barrier();

        STAGE_A8(nb, 1, kn);
        __builtin_amdgcn_s_barrier();
        MFMA_PHASE8(3, bf1);
        VMWAIT8(4);
        __builtin_amdgcn_s_barrier();
    }

    {
        const int b = (NT - 1) & 1;
        READ_AF8(b, 0);
        READ_BF8(bf0, b, 0);
        __builtin_amdgcn_s_barrier();
        MFMA_PHASE8(0, bf0);
        VMWAIT8(2);
        __builtin_amdgcn_s_barrier();

        READ_BF8(bf1, b, 1);
        __builtin_amdgcn_s_barrier();
        MFMA_PHASE8(1, bf1);
        VMWAIT8(0);
        __builtin_amdgcn_s_barrier();

        READ_AF8(b, 1);
        __builtin_amdgcn_s_barrier();
        MFMA_PHASE8(2, bf0);
        __builtin_amdgcn_s_barrier();
        MFMA_PHASE8(3, bf1);
    }

    #pragma unroll
    for (int p = 0; p < 4; ++p) {
        const int rbase = m0 + (p >> 1) * 128 + wm * 64 + quad * 4;
        const int cbase = n0 + (p & 1) * 128 + wn4 * 32 + mlane;
        #pragma unroll
        for (int mf = 0; mf < 4; ++mf)
            #pragma unroll
            for (int nf = 0; nf < 2; ++nf)
                #pragma unroll
                for (int reg = 0; reg < 4; ++reg)
                    Cout[(size_t)(rbase + mf * 16 + reg) * Nn + cbase + nf * 16] = f2b(acc[p][mf][nf][reg]);
    }
}

// ---------------------------------------------------------------------------
// FUSED stats + V-transpose.
// R19 (this round): OCCUPANCY via LDS cut. R11 counters: 80us, MfmaUtil 17,
// VALUBusy 40, Occupancy 19.5% — latency-bound; LDS 47.6KB (qt[4][64x72] =
// 36.9KB of it) caps residency at 2-3 blocks/CU. Per-wave Q tile shrunk
// 64 -> 32 rows (16 iters instead of 8): qt[4][32x72] = 18.4KB, total
// ~28.9KB -> 5 blocks/CU = 20 waves/CU (matches the 88-VGPR cap). Per-wave
// totals (staging writes, frag reads, MFMA, exp2) are IDENTICAL — q4
// amortization preserved; only prefetch block halves (pq[4]).
// ---------------------------------------------------------------------------
__global__ __launch_bounds__(256) void attn_stats_vt(const u16* __restrict__ qkvb,
                                                     u16* __restrict__ vT) {
    __shared__ u16 kt[64 * 72];
    __shared__ u16 qt[4][32 * 72];
    __shared__ float red[4][64];
    __shared__ float li[64];

    const int tid = threadIdx.x;
    const int lane = tid & 63, wave = tid >> 6;
    const int mlane = lane & 15, quad = lane >> 4;
    const int id = blockIdx.x;
    const int bh = (id & 7) * 8 + ((id >> 3) & 7);
    const int b = bh >> 4, h = bh & 15;
    const int j0 = (id >> 6) * 64;

    const u16* qbase = qkvb + (size_t)b * N_ * RS_ + h * DH_;
    const u16* kbase = qbase + HID_;
    const u16* vbase = qbase + 2 * HID_;

    for (int idx = tid; idx < 512; idx += 256) {
        int r = idx >> 3, d8 = (idx & 7) * 8;
        *(u16x8*)&kt[r * 72 + d8] = *(const u16x8*)&kbase[(size_t)(j0 + r) * RS_ + d8];
    }
    __syncthreads();

    bf16x8 kf[4][2];
    #pragma unroll
    for (int t = 0; t < 4; t++)
        #pragma unroll
        for (int ks = 0; ks < 2; ks++)
            kf[t][ks] = *(const bf16x8*)&kt[(t * 16 + mlane) * 72 + ks * 32 + quad * 8];

    f32x4 acc[4] = {};   // acc[ktile][reg] : key = ktile*16 + quad*4 + reg
    u16* qw = &qt[wave][0];

    const int prr = lane >> 3, pd8 = (lane & 7) * 8;   // per-lane staging coords
    u16x8 pq[4];
    #pragma unroll
    for (int t = 0; t < 4; t++)
        pq[t] = *(const u16x8*)&qbase[(size_t)(wave * 32 + t * 8 + prr) * RS_ + pd8];

    for (int i0 = wave * 32; i0 < N_; i0 += 128) {
        #pragma unroll
        for (int t = 0; t < 4; t++)
            *(u16x8*)&qw[(t * 8 + prr) * 72 + pd8] = pq[t];
        int in = i0 + 128;
        if (in < N_) {
            #pragma unroll
            for (int t = 0; t < 4; t++)
                pq[t] = *(const u16x8*)&qbase[(size_t)(in + t * 8 + prr) * RS_ + pd8];
        }
        #pragma unroll
        for (int q4 = 0; q4 < 2; q4++) {
            bf16x8 bq0 = *(const bf16x8*)&qw[(q4 * 16 + mlane) * 72 + quad * 8];
            bf16x8 bq1 = *(const bf16x8*)&qw[(q4 * 16 + mlane) * 72 + 32 + quad * 8];
            #pragma unroll
            for (int t = 0; t < 4; t++) {
                f32x4 z = {0.f, 0.f, 0.f, 0.f};
                z = __builtin_amdgcn_mfma_f32_16x16x32_bf16(kf[t][0], bq0, z, 0, 0, 0);
                z = __builtin_amdgcn_mfma_f32_16x16x32_bf16(kf[t][1], bq1, z, 0, 0, 0);
                #pragma unroll
                for (int reg = 0; reg < 4; reg++)
                    acc[t][reg] += __builtin_amdgcn_exp2f(z[reg]);
            }
        }
    }

    #pragma unroll
    for (int t = 0; t < 4; t++)
        #pragma unroll
        for (int reg = 0; reg < 4; reg++) {
            float v = acc[t][reg];
            v += __shfl_xor(v, 1, 64);
            v += __shfl_xor(v, 2, 64);
            v += __shfl_xor(v, 4, 64);
            v += __shfl_xor(v, 8, 64);
            if (mlane == 0) red[wave][t * 16 + quad * 4 + reg] = v;
        }
    __syncthreads();
    if (tid < 64) {
        float l = red[0][tid] + red[1][tid] + red[2][tid] + red[3][tid];
        li[tid] = 1.0f / l;
    }

    // --- phase 2: V tile scale + transpose (reuse kt buffer) ---
    for (int idx = tid; idx < 512; idx += 256) {
        int r = idx >> 3, d8 = (idx & 7) * 8;
        *(u16x8*)&kt[r * 72 + d8] = *(const u16x8*)&vbase[(size_t)(j0 + r) * RS_ + d8];
    }
    __syncthreads();   // covers li writes and V staging
    {
        int d = tid >> 2, j16 = (tid & 3) * 16;
        u16x8 p0, p1;
        #pragma unroll
        for (int u = 0; u < 8; u++) {
            p0[u] = f2b(b2f(kt[(j16 + u) * 72 + d]) * li[j16 + u]);
            p1[u] = f2b(b2f(kt[(j16 + 8 + u) * 72 + d]) * li[j16 + 8 + u]);
        }
        size_t o = ((size_t)bh * DH_ + d) * N_ + j0 + j16;
        *(u16x8*)&vT[o] = p0;
        *(u16x8*)&vT[o + 8] = p1;
    }
}

// ---------------------------------------------------------------------------
// Apply (unchanged R16: 256 q/block, 8 waves, K/V dbuf, setprio, XCD swizzle).
// ---------------------------------------------------------------------------
__global__ __launch_bounds__(512) void attn_apply(const u16* __restrict__ qkvb,
                                                  const u16* __restrict__ vT,
                                                  u16* __restrict__ yb) {
    __shared__ u16 S[256 * 72];

    const int tid = threadIdx.x;
    const int lane = tid & 63, wave = tid >> 6;
    const int m31 = lane & 31, half = lane >> 5;

    const int id = blockIdx.x;
    const int v = (id & 7) * 64 + (id >> 3);
    const int bh = v >> 3, b = bh >> 4, h = bh & 15;
    const int i0 = (v & 7) * 256;

    const u16* qbase = qkvb + (size_t)b * N_ * RS_ + h * DH_;
    const u16* kbase = qbase + HID_;
    const u16* vbase = vT + (size_t)bh * DH_ * N_;

    for (int idx = tid; idx < 2048; idx += 512) {
        int r = idx >> 3, d8 = (idx & 7) * 8;
        *(u16x8*)&S[r * 72 + d8] = *(const u16x8*)&qbase[(size_t)(i0 + r) * RS_ + d8];
    }
    __syncthreads();

    bf16x8 qf[4];
    #pragma unroll
    for (int ks = 0; ks < 4; ks++)
        qf[ks] = *(const bf16x8*)&S[(wave * 32 + m31) * 72 + ks * 16 + half * 8];

    const int pr = tid >> 3, pc8 = (tid & 7) * 8;
    u16x8 pk, pv;
    pk = *(const u16x8*)&kbase[(size_t)pr * RS_ + pc8];
    pv = *(const u16x8*)&vbase[(size_t)pr * N_ + pc8];

    __syncthreads();

    f32x16 yacc[2] = {};

    int cur = 0;
    for (int j0 = 0; j0 < N_; j0 += 64, cur ^= 1) {
        u16* Sb = &S[cur * 128 * 72];
        *(u16x8*)&Sb[pr * 72 + pc8]        = pk;
        *(u16x8*)&Sb[(pr + 64) * 72 + pc8] = pv;
        __syncthreads();

        int jn = j0 + 64;
        if (jn < N_) {
            pk = *(const u16x8*)&kbase[(size_t)(jn + pr) * RS_ + pc8];
            pv = *(const u16x8*)&vbase[(size_t)pr * N_ + jn + pc8];
        }

        bf16x8 pa[4];
        #pragma unroll
        for (int kt = 0; kt < 2; kt++) {
            bf16x8 ka[4];
            #pragma unroll
            for (int ks = 0; ks < 4; ks++)
                ka[ks] = *(const bf16x8*)&Sb[(kt * 32 + m31) * 72 + ks * 16 + half * 8];

            f32x16 sc = {};
            __builtin_amdgcn_s_setprio(1);
            #pragma unroll
            for (int ks = 0; ks < 4; ks++)
                sc = __builtin_amdgcn_mfma_f32_32x32x16_bf16(ka[ks], qf[ks], sc, 0, 0, 0);
            __builtin_amdgcn_s_setprio(0);

            u32 P[4][2];
            #pragma unroll
            for (int rb = 0; rb < 4; rb++)
                #pragma unroll
                for (int pp = 0; pp < 2; pp++) {
                    float e0 = __builtin_amdgcn_exp2f(sc[4 * rb + 2 * pp]);
                    float e1 = __builtin_amdgcn_exp2f(sc[4 * rb + 2 * pp + 1]);
                    P[rb][pp] = pack2bf(e0, e1);
                }
            #pragma unroll
            for (int ksl = 0; ksl < 2; ksl++) {
                pl32swap(P[2 * ksl][0], P[2 * ksl + 1][0]);
                pl32swap(P[2 * ksl][1], P[2 * ksl + 1][1]);
                union { u32 u[4]; bf16x8 v; } cv;
                cv.u[0] = P[2 * ksl][0];
                cv.u[1] = P[2 * ksl][1];
                cv.u[2] = P[2 * ksl + 1][0];
                cv.u[3] = P[2 * ksl + 1][1];
                pa[2 * kt + ksl] = cv.v;
            }
        }

        __builtin_amdgcn_s_setprio(1);
        #pragma unroll
        for (int ks16 = 0; ks16 < 4; ks16++) {
            bf16x8 vb0 = *(const bf16x8*)&Sb[(64 + m31) * 72 + ks16 * 16 + half * 8];
            bf16x8 vb1 = *(const bf16x8*)&Sb[(96 + m31) * 72 + ks16 * 16 + half * 8];
            yacc[0] = __builtin_amdgcn_mfma_f32_32x32x16_bf16(pa[ks16], vb0, yacc[0], 0, 0, 0);
            yacc[1] = __builtin_amdgcn_mfma_f32_32x32x16_bf16(pa[ks16], vb1, yacc[1], 0, 0, 0);
        }
        __builtin_amdgcn_s_setprio(0);
    }

    #pragma unroll
    for (int dt = 0; dt < 2; dt++)
        #pragma unroll
        for (int reg = 0; reg < 16; reg++) {
            int q = i0 + wave * 32 + (reg & 3) + 8 * (reg >> 2) + 4 * half;
            yb[((size_t)b * N_ + q) * HID_ + h * DH_ + dt * 32 + m31] = f2b(yacc[dt][reg]);
        }
}

// ---------------------------------------------------------------------------
extern "C" void kernel_launch(void* const* d_in, const int* in_sizes, int n_in,
                              void* d_out, int out_size, void* d_ws, size_t ws_size,
                              hipStream_t stream) {
    (void)in_sizes; (void)n_in; (void)out_size; (void)ws_size;

    const float* x     = (const float*)d_in[0];
    const float* w_qkv = (const float*)d_in[1];
    const float* w_out = (const float*)d_in[2];
    const float* b_out = (const float*)d_in[3];

    u16* xb    = (u16*)d_ws;                          // [8192][1024]
    u16* wqkvT = xb    + (size_t)8192 * 1024;         // [3072][1024]
    u16* woutT = wqkvT + (size_t)3072 * 1024;         // [1024][1024]
    u16* qkvb  = woutT + (size_t)1024 * 1024;         // [8192][3072]
    u16* vTb   = qkvb  + (size_t)8192 * 3072;         // [64][64][2048]
    u16* yb    = vTb   + (size_t)64 * 64 * 2048;      // [8192][1024]

    // fused prep launch (cast + both weight transposes)
    prep<<<5120, 256, 0, stream>>>(x, xb, w_qkv, wqkvT, w_out, woutT);

    // 8-phase 256^2 counted-vmcnt GEMM for QKV. grid = 32x12 = 384.
    gemm_bt8<<<384, 512, 0, stream>>>(xb, wqkvT, qkvb, 8192, 3072, 1024);

    // fused stats + V-transpose: grid = 32 j-tiles * 64 heads, XCD-swizzled
    attn_stats_vt<<<32 * 64, 256, 0, stream>>>(qkvb, vTb);

    // attn apply: 256 q/block, 8 waves, 1-D grid 512, XCD swizzle
    attn_apply<<<512, 512, 0, stream>>>(qkvb, vTb, yb);

    // out-projection: verified 128^2 BK=64 kernel (grid 512, good fit)
    gemm_bt<0><<<64 * 8, 256, 0, stream>>>(
        yb, woutT, b_out, d_out, 8192, 1024, 1024);
}